// Round 5
// baseline (2715.836 us; speedup 1.0000x reference)
//
#include <hip/hip_runtime.h>
#include <hip/hip_bf16.h>

// FNO2d: B=16, CIN=20, H=W=256, WIDTH=64, M1=M2=16, NLAYERS=4, FC_HID=128, COUT=20
// Round 8: two occupancy levers.
// proj (361us, VALUBusy 77%, occ 45%): red[4][20][128] 40KB -> red[20][128] 10KB
// + ds_add_f32 (LDS atomicAdd). LDS 73->43KB -> 3 blocks/CU (24 waves, 75% occ).
// dfty (ds-heavy, 69KB LDS -> 2 blocks/CU, 2 waves/SIMD): Ws[256][32] 32KB table
// -> per-yc-chunk Wc[64][32] 8KB rebuild from cs2/sn2. LDS 69->45KB -> 3 blocks/CU.
//
// Per-sample workspace (floats): h 4,194,304 | T/G 524,288 | X2 65,536 | Y2 65,536
// = 4,849,664 floats (19.4 MB); CB=16 -> 310 MB.

#define HW_TOT 65536
#define PI2_256 0.024543692606170259758f  // 2*pi/256

__device__ __forceinline__ float gelu_exact(float v) {
    return 0.5f * v * (1.0f + erff(v * 0.70710678118654752440f));
}
// Branch-free gelu: erf via Abramowitz-Stegun 7.1.26 (|abs err| <= 1.5e-7).
__device__ __forceinline__ float gelu_fast(float v) {
    float z  = v * 0.70710678118654752440f;
    float az = fabsf(z);
    float t  = __builtin_amdgcn_rcpf(fmaf(0.3275911f, az, 1.0f));
    float p  = t * (0.254829592f + t * (-0.284496736f + t * (1.421413741f +
               t * (-1.453152027f + t * 1.061405429f))));
    float e  = __expf(-az * az);
    float er = copysignf(1.0f - p * e, z);
    return 0.5f * v * (1.0f + er);
}
#define F4COMP(v, k) ((k)==0?(v).x:(k)==1?(v).y:(k)==2?(v).z:(v).w)

// ---------------- 1x1 conv (lift)
template<int CI, int CO, int WS>
__global__ void __launch_bounds__(256) conv1x1_kernel(
    const float* __restrict__ in, const float* __restrict__ w,
    const float* __restrict__ bias, float* __restrict__ out)
{
    const int b = blockIdx.y;
    const int p = blockIdx.x * 256 + threadIdx.x;
    const float* inp = in + (size_t)b * CI * HW_TOT + p;
    float acc[CO];
#pragma unroll
    for (int o = 0; o < CO; ++o) acc[o] = bias[o];
    for (int ci = 0; ci < CI; ++ci) {
        float hv = inp[(size_t)ci * HW_TOT];
#pragma unroll
        for (int o = 0; o < CO; ++o)
            acc[o] = fmaf(w[o * WS + ci], hv, acc[o]);
    }
    float* op = out + (size_t)b * CO * HW_TOT + p;
#pragma unroll
    for (int o = 0; o < CO; ++o) op[(size_t)o * HW_TOT] = acc[o];
}

// ---------------- forward DFT over y as GEMM: T[row*32 + 2ky+c] = sum_y h[row,y]*W[y][2ky+c]
// W[y][2ky] = cos(2pi y ky/256), W[y][2ky+1] = -sin(...). Block: 128 rows x 32 j, 256 thr.
// Thread: jg = t&7 (j = 4jg..+3), rg = t>>3 (rows rg+32k, k<4). 16 acc.
// R8: twiddles rebuilt per 64-y chunk into Wc[64][32] (8KB) instead of a resident
// Ws[256][32] (32KB): LDS 45KB -> 3 blocks/CU (was 2).
__global__ void __launch_bounds__(256) dfty_kernel(
    const float* __restrict__ h, float* __restrict__ T)
{
    __shared__ float As[128][68];     // y-chunk of 64, padded (34.8 KB)
    __shared__ float Wc[64][32];      // per-chunk twiddles (8 KB)
    __shared__ float cs2[256], sn2[256];
    const int t = threadIdx.x;
    {
        float a = (float)t * PI2_256;
        cs2[t] = cosf(a); sn2[t] = sinf(a);
    }
    __syncthreads();

    const size_t rowbase = (size_t)blockIdx.x * 128;
    const int jg = t & 7, rg = t >> 3;
    float acc[4][4];
#pragma unroll
    for (int k = 0; k < 4; ++k)
#pragma unroll
        for (int q = 0; q < 4; ++q) acc[k][q] = 0.0f;

    for (int yc = 0; yc < 256; yc += 64) {
        if (yc) __syncthreads();   // protect As/Wc from previous iteration's readers
        // stage As[128][64]: 2048 float4; lane-consecutive = y-consecutive (coalesced)
#pragma unroll
        for (int it = 0; it < 8; ++it) {
            int idx = t + 256 * it;
            int rr = idx >> 4, c4 = idx & 15;
            float4 v = *(const float4*)(h + (rowbase + rr) * 256 + yc + c4 * 4);
            *(float4*)&As[rr][c4 * 4] = v;
        }
        // build Wc for this chunk: Wc[yl][2ky+c] for y = yc+yl
#pragma unroll
        for (int it = 0; it < 8; ++it) {
            int i = t + 256 * it;
            int yl = i >> 5, j = i & 31, ky = j >> 1;
            int m = ((yc + yl) * ky) & 255;
            Wc[yl][j] = (j & 1) ? -sn2[m] : cs2[m];
        }
        __syncthreads();
#pragma unroll 2
        for (int yy = 0; yy < 64; yy += 4) {
            float4 wv[4], av[4];
#pragma unroll
            for (int q = 0; q < 4; ++q) wv[q] = *(const float4*)&Wc[yy + q][jg * 4];
#pragma unroll
            for (int k = 0; k < 4; ++k) av[k] = *(const float4*)&As[rg + 32 * k][yy];
#pragma unroll
            for (int k = 0; k < 4; ++k)
#pragma unroll
                for (int q = 0; q < 4; ++q) {
                    float a = F4COMP(av[k], q);
                    acc[k][0] = fmaf(a, wv[q].x, acc[k][0]);
                    acc[k][1] = fmaf(a, wv[q].y, acc[k][1]);
                    acc[k][2] = fmaf(a, wv[q].z, acc[k][2]);
                    acc[k][3] = fmaf(a, wv[q].w, acc[k][3]);
                }
        }
    }
#pragma unroll
    for (int k = 0; k < 4; ++k) {
        float4 v = make_float4(acc[k][0], acc[k][1], acc[k][2], acc[k][3]);
        *(float4*)&T[(rowbase + rg + 32 * k) * 32 + jg * 4] = v;
    }
}

// ---------------- forward DFT over x: X[bc,kxi,ky] = sum_x T[bc,x,ky] * e^{-2pi i kx x/256}
__global__ void __launch_bounds__(512) dft2_kernel(
    const float2* __restrict__ T2, float2* __restrict__ X2)
{
    __shared__ float cs[256], sn[256];
    const int t = threadIdx.x;
    if (t < 256) {
        float a = (float)t * PI2_256;
        cs[t] = cosf(a); sn[t] = sinf(a);
    }
    __syncthreads();
    const int bc = blockIdx.x;
    const int ky = t & 15, kxi = t >> 4;
    const int kx = (kxi < 16) ? kxi : (224 + kxi);
    const float2* Tp = T2 + (size_t)bc * 4096 + ky;
    float xr = 0.0f, xi = 0.0f;
    int m = 0;
    for (int x = 0; x < 256; ++x) {
        float2 tv = Tp[(size_t)x * 16];
        float c = cs[m], s = sn[m];
        xr = fmaf(tv.x, c, fmaf(tv.y, s, xr));
        xi = fmaf(tv.y, c, fmaf(-tv.x, s, xi));
        m = (m + kx) & 255;
    }
    X2[(size_t)bc * 512 + t] = make_float2(xr, xi);
}

// ---------------- complex mode mixing
__global__ void __launch_bounds__(512) mix_kernel(
    const float2* __restrict__ X2, float2* __restrict__ Y2,
    const float* __restrict__ w1r, const float* __restrict__ w1i,
    const float* __restrict__ w2r, const float* __restrict__ w2i, int layer)
{
    const int bo = blockIdx.x;
    const int b = bo >> 6, o = bo & 63;
    const int t = threadIdx.x;
    const int ky = t & 15, kxi = t >> 4;
    const bool top = (kxi < 16);
    const int kxm = top ? kxi : (kxi - 16);
    const float* wr = top ? w1r : w2r;
    const float* wi = top ? w1i : w2i;
    float yr = 0.0f, yi = 0.0f;
    for (int i = 0; i < 64; ++i) {
        float2 xv = X2[((size_t)(b * 64 + i) * 32 + kxi) * 16 + ky];
        size_t widx = (((size_t)layer * 64 + i) * 64 + o) * 256 + (kxm * 16 + ky);
        float wrv = wr[widx], wiv = wi[widx];
        yr = fmaf(xv.x, wrv, fmaf(-xv.y, wiv, yr));
        yi = fmaf(xv.x, wiv, fmaf(xv.y, wrv, yi));
    }
    Y2[((size_t)(b * 64 + o) * 32 + kxi) * 16 + ky] = make_float2(yr, yi);
}

// ---------------- inverse DFT over x
__global__ void __launch_bounds__(256) idft1_kernel(
    const float2* __restrict__ Y2, float2* __restrict__ G2)
{
    __shared__ float cs[256], sn[256];
    const int t = threadIdx.x;
    {
        float a = (float)t * PI2_256;
        cs[t] = cosf(a); sn[t] = sinf(a);
    }
    __syncthreads();
    const int bo = blockIdx.x >> 4;
    const int xc = blockIdx.x & 15;
    const int ky = t & 15, xo = t >> 4;
    const int x = xc * 16 + xo;
    const float2* Yp = Y2 + (size_t)bo * 512 + ky;
    float gr = 0.0f, gi = 0.0f;
    for (int kxi = 0; kxi < 32; ++kxi) {
        float2 yv = Yp[(size_t)kxi * 16];
        int kx = (kxi < 16) ? kxi : (224 + kxi);
        int m = (kx * x) & 255;
        float c = cs[m], s = sn[m];
        gr = fmaf(yv.x, c, fmaf(-yv.y, s, gr));
        gi = fmaf(yv.x, s, fmaf(yv.y, c, gi));
    }
    G2[((size_t)bo * 256 + x) * 16 + ky] = make_float2(gr, gi);
}

// ---------------- fused pointwise conv + iDFT-y + add + GELU, in place on h.
__global__ void __launch_bounds__(1024) pwcomb_kernel(
    float* __restrict__ h, const float2* __restrict__ G2,
    const float* __restrict__ pw_w, const float* __restrict__ pw_b,
    int layer, int do_gelu)
{
    __shared__ float hs[64][256];     // [ci][y] 64 KB
    __shared__ float Wt[64][65];      // [ci][o] transposed, padded (16.6 KB)
    __shared__ float Gt[32][64];      // [j'][o] 8 KB
    __shared__ float Pt[32][256];     // [j'][y] 32 KB
    __shared__ float cs[256], sn[256];
    const int t = threadIdx.x;
    const int b = blockIdx.x >> 8;
    const int x = blockIdx.x & 255;
    if (t < 256) {
        float a = (float)t * PI2_256;
        cs[t] = cosf(a); sn[t] = sinf(a);
    }
    __syncthreads();

    // Wt[ci][o] from pw_w[layer][o][ci]
    const float* wl = pw_w + layer * 4096;
    for (int i = t; i < 4096; i += 1024) { int o = i >> 6, ci = i & 63; Wt[ci][o] = wl[i]; }
    // Gt from G2
    {
        int o = t >> 4, ky = t & 15;
        float2 g = G2[((size_t)(b * 64 + o) * 256 + x) * 16 + ky];
        Gt[2 * ky][o] = g.x;
        Gt[2 * ky + 1][o] = g.y;
    }
    // Pt[j'][y]: j'=2ky -> wk*cos(2pi ky y/256); j'=2ky+1 -> -wk*sin(...)
    const float inv = 1.0f / 65536.0f;
#pragma unroll
    for (int it = 0; it < 8; ++it) {
        int i = t + 1024 * it;
        int jp = i >> 8, y = i & 255, ky = jp >> 1;
        int m = (ky * y) & 255;
        float wk = (ky == 0) ? inv : 2.0f * inv;
        Pt[jp][y] = (jp & 1) ? -wk * sn[m] : wk * cs[m];
    }
    // stage hs (all reads of h precede the barrier; writes after -> in-place safe)
#pragma unroll
    for (int it = 0; it < 4; ++it) {
        int idx = t + 1024 * it;
        int ci = idx >> 6, c4 = idx & 63;
        float4 v = *(const float4*)(h + ((size_t)(b * 64 + ci) * 256 + x) * 256 + c4 * 4);
        *(float4*)&hs[ci][c4 * 4] = v;
    }
    __syncthreads();

    const int og = t & 15, yg = t >> 4;
    const float* bl = pw_b + layer * 64;
    float acc[4][4];   // [yj][oj]
#pragma unroll
    for (int oj = 0; oj < 4; ++oj) {
        float bv = bl[og * 4 + oj];
#pragma unroll
        for (int yj = 0; yj < 4; ++yj) acc[yj][oj] = bv;
    }
    // conv part: K = 64
    for (int ci = 0; ci < 64; ++ci) {
        float4 hv = *(const float4*)&hs[ci][yg * 4];
        float4 wv = *(const float4*)&Wt[ci][og * 4];
#pragma unroll
        for (int yj = 0; yj < 4; ++yj) {
            float a = F4COMP(hv, yj);
            acc[yj][0] = fmaf(a, wv.x, acc[yj][0]);
            acc[yj][1] = fmaf(a, wv.y, acc[yj][1]);
            acc[yj][2] = fmaf(a, wv.z, acc[yj][2]);
            acc[yj][3] = fmaf(a, wv.w, acc[yj][3]);
        }
    }
    // spectral part: K = 32
#pragma unroll 4
    for (int jp = 0; jp < 32; ++jp) {
        float4 pv = *(const float4*)&Pt[jp][yg * 4];
        float4 gv = *(const float4*)&Gt[jp][og * 4];
#pragma unroll
        for (int yj = 0; yj < 4; ++yj) {
            float a = F4COMP(pv, yj);
            acc[yj][0] = fmaf(a, gv.x, acc[yj][0]);
            acc[yj][1] = fmaf(a, gv.y, acc[yj][1]);
            acc[yj][2] = fmaf(a, gv.z, acc[yj][2]);
            acc[yj][3] = fmaf(a, gv.w, acc[yj][3]);
        }
    }
    // epilogue: gelu + store (float4 per o-row)
#pragma unroll
    for (int oj = 0; oj < 4; ++oj) {
        float4 v;
        v.x = acc[0][oj]; v.y = acc[1][oj]; v.z = acc[2][oj]; v.w = acc[3][oj];
        if (do_gelu) {
            v.x = gelu_fast(v.x); v.y = gelu_fast(v.y);
            v.z = gelu_fast(v.z); v.w = gelu_fast(v.w);
        }
        *(float4*)&h[((size_t)(b * 64 + og * 4 + oj) * 256 + x) * 256 + yg * 4] = v;
    }
}

// ---------------- tiny transpose: w1t[ci][hd] = fc1_w[hd][ci]  (64 x 128)
__global__ void __launch_bounds__(256) transpose_w1_kernel(
    const float* __restrict__ w1, float* __restrict__ w1t)
{
    int i = blockIdx.x * 256 + threadIdx.x;   // 8192 elements
    int ci = i >> 7, hd = i & 127;
    w1t[i] = w1[hd * 64 + ci];
}

// ---------------- fused projection: out = fc2(gelu(fc1(h))) per pixel.
// 512 thr, block = 128 px. Thread = 1 px x 32 hd (px = t&127, wave wv = t>>7,
// hd = wv*32..+31 wave-uniform -> w1t/w2 rows via s_load). fc1: 1 ds_read_b32
// per ci + 32 reg FMA. gelu in regs. fc2: 20 partial dots, then ds_add_f32 into
// red[20][128] (init = b2). R8: red 40KB -> 10KB; LDS 42KB -> 3 blocks/CU.
__global__ void __launch_bounds__(512, 4) proj_kernel(
    const float* __restrict__ h,
    const float* __restrict__ w1t, const float* __restrict__ b1,
    const float* __restrict__ w2, const float* __restrict__ b2,
    float* __restrict__ out)
{
    __shared__ float hs[64][128];        // 32 KB
    __shared__ float red[20][128];       // 10 KB
    const int t = threadIdx.x;
    const int blk = blockIdx.x;
    const int b = blk >> 9;                 // 512 blocks per sample
    const int p0 = (blk & 511) << 7;        // pixel base

    // stage hs: 64 rows x 128 px = 2048 float4, coalesced
    {
        const float* hp = h + (size_t)b * 64 * HW_TOT + p0;
#pragma unroll
        for (int it = 0; it < 4; ++it) {
            int idx = t + 512 * it;
            int ci = idx >> 5, c4 = idx & 31;
            float4 v = *(const float4*)(hp + (size_t)ci * HW_TOT + c4 * 4);
            *(float4*)&hs[ci][c4 * 4] = v;
        }
    }
    // init red[o][px] = b2[o]  (2560 floats)
#pragma unroll
    for (int it = 0; it < 5; ++it) {
        int i = t + 512 * it;
        if (i < 2560) red[i >> 7][i & 127] = b2[i >> 7];
    }
    __syncthreads();

    const int px = t & 127;
    const int wv = __builtin_amdgcn_readfirstlane(t >> 7);  // 0..3, wave-uniform
    const int hd0 = wv * 32;

    // fc1: acc[k] = b1[hd0+k] + sum_ci w1[hd0+k][ci] * h[ci][px]
    float acc[32];
#pragma unroll
    for (int k = 0; k < 32; ++k) acc[k] = b1[hd0 + k];
#pragma unroll 2
    for (int ci = 0; ci < 64; ++ci) {
        float a = hs[ci][px];
        const float* wr = w1t + ci * 128 + hd0;   // uniform -> s_load
#pragma unroll
        for (int k = 0; k < 32; ++k) acc[k] = fmaf(wr[k], a, acc[k]);
    }
    // gelu in registers
#pragma unroll
    for (int k = 0; k < 32; ++k) acc[k] = gelu_fast(acc[k]);

    // fc2 partials over this wave's 32 hd, accumulate via LDS atomic add
#pragma unroll
    for (int o = 0; o < 20; ++o) {
        const float* w2r = w2 + o * 128 + hd0;    // uniform -> s_load
        float s0 = 0.0f, s1 = 0.0f;
#pragma unroll
        for (int k = 0; k < 32; k += 2) {
            s0 = fmaf(w2r[k], acc[k], s0);
            s1 = fmaf(w2r[k + 1], acc[k + 1], s1);
        }
        atomicAdd(&red[o][px], s0 + s1);          // ds_add_f32
    }
    __syncthreads();

    const int og = t >> 7;
    float* op = out + (size_t)b * 20 * HW_TOT + p0 + px;
#pragma unroll
    for (int j = 0; j < 5; ++j) {
        int o = og * 5 + j;
        op[(size_t)o * HW_TOT] = red[o][px];
    }
}

extern "C" void kernel_launch(void* const* d_in, const int* in_sizes, int n_in,
                              void* d_out, int out_size, void* d_ws, size_t ws_size,
                              hipStream_t stream)
{
    const float* x     = (const float*)d_in[0];
    const float* w1r   = (const float*)d_in[1];
    const float* w1i   = (const float*)d_in[2];
    const float* w2r   = (const float*)d_in[3];
    const float* w2i   = (const float*)d_in[4];
    const float* pw_w  = (const float*)d_in[5];
    const float* pw_b  = (const float*)d_in[6];
    const float* fc0_w = (const float*)d_in[7];
    const float* fc0_b = (const float*)d_in[8];
    const float* fc1_w = (const float*)d_in[9];
    const float* fc1_b = (const float*)d_in[10];
    const float* fc2_w = (const float*)d_in[11];
    const float* fc2_b = (const float*)d_in[12];
    float* out = (float*)d_out;
    float* ws  = (float*)d_ws;

    const size_t per_sample_floats = 4849664;
    int CB = 16;
    while (CB > 1 && (size_t)CB * per_sample_floats * 4 > ws_size) CB >>= 1;

    float*  h  = ws;
    float*  T  = ws + (size_t)CB * 4194304;
    float2* T2 = (float2*)T;
    float2* X2 = (float2*)(T + (size_t)CB * 524288);
    float2* Y2 = (float2*)(T + (size_t)CB * 524288 + (size_t)CB * 65536);
    float2* G2 = T2;   // reuse

    for (int c0 = 0; c0 < 16; c0 += CB) {
        const float* xc = x + (size_t)c0 * 20 * HW_TOT;
        float* oc = out + (size_t)c0 * 20 * HW_TOT;

        conv1x1_kernel<20, 64, 20>
            <<<dim3(256, CB), 256, 0, stream>>>(xc, fc0_w, fc0_b, h);

        for (int l = 0; l < 4; ++l) {
            dfty_kernel <<<CB * 128, 256, 0, stream>>>(h, T);
            dft2_kernel <<<CB * 64, 512, 0, stream>>>(T2, X2);
            mix_kernel  <<<CB * 64, 512, 0, stream>>>(X2, Y2, w1r, w1i, w2r, w2i, l);
            idft1_kernel<<<CB * 64 * 16, 256, 0, stream>>>(Y2, G2);
            pwcomb_kernel<<<CB * 256, 1024, 0, stream>>>(h, G2, pw_w, pw_b, l, (l < 3) ? 1 : 0);
        }

        // T/G2 region is dead after the last pwcomb: reuse for w1^T
        transpose_w1_kernel<<<32, 256, 0, stream>>>(fc1_w, T);
        proj_kernel<<<CB * 512, 512, 0, stream>>>(h, T, fc1_b, fc2_w, fc2_b, oc);
    }
}

// Round 6
// 2649.926 us; speedup vs baseline: 1.0249x; 1.0249x over previous
//
#include <hip/hip_runtime.h>
#include <hip/hip_bf16.h>

// FNO2d: B=16, CIN=20, H=W=256, WIDTH=64, M1=M2=16, NLAYERS=4, FC_HID=128, COUT=20
// Round 9: R8 post-mortem -- dfty Wc-rebuild was a WIN (-160us aggregate), but
// proj's ds_add_f32 reduction REGRESSED 361->533 (VALU-busy time identical at
// ~270us; the atomics' RMW serialization before the barrier added pure stall).
// Fix: restore R7's contention-free plain-write reduction, but as a 2-stage tree
// (red[2][20][128], 20KB): wv2/3 write partials, wv0/1 add in regs, wv1 writes
// combined, wv0 stores. LDS 52KB -> 3 blocks/CU (24 waves) with zero atomics.
//
// Per-sample workspace (floats): h 4,194,304 | T/G 524,288 | X2 65,536 | Y2 65,536
// = 4,849,664 floats (19.4 MB); CB=16 -> 310 MB.

#define HW_TOT 65536
#define PI2_256 0.024543692606170259758f  // 2*pi/256

__device__ __forceinline__ float gelu_exact(float v) {
    return 0.5f * v * (1.0f + erff(v * 0.70710678118654752440f));
}
// Branch-free gelu: erf via Abramowitz-Stegun 7.1.26 (|abs err| <= 1.5e-7).
__device__ __forceinline__ float gelu_fast(float v) {
    float z  = v * 0.70710678118654752440f;
    float az = fabsf(z);
    float t  = __builtin_amdgcn_rcpf(fmaf(0.3275911f, az, 1.0f));
    float p  = t * (0.254829592f + t * (-0.284496736f + t * (1.421413741f +
               t * (-1.453152027f + t * 1.061405429f))));
    float e  = __expf(-az * az);
    float er = copysignf(1.0f - p * e, z);
    return 0.5f * v * (1.0f + er);
}
#define F4COMP(v, k) ((k)==0?(v).x:(k)==1?(v).y:(k)==2?(v).z:(v).w)

// ---------------- 1x1 conv (lift)
template<int CI, int CO, int WS>
__global__ void __launch_bounds__(256) conv1x1_kernel(
    const float* __restrict__ in, const float* __restrict__ w,
    const float* __restrict__ bias, float* __restrict__ out)
{
    const int b = blockIdx.y;
    const int p = blockIdx.x * 256 + threadIdx.x;
    const float* inp = in + (size_t)b * CI * HW_TOT + p;
    float acc[CO];
#pragma unroll
    for (int o = 0; o < CO; ++o) acc[o] = bias[o];
    for (int ci = 0; ci < CI; ++ci) {
        float hv = inp[(size_t)ci * HW_TOT];
#pragma unroll
        for (int o = 0; o < CO; ++o)
            acc[o] = fmaf(w[o * WS + ci], hv, acc[o]);
    }
    float* op = out + (size_t)b * CO * HW_TOT + p;
#pragma unroll
    for (int o = 0; o < CO; ++o) op[(size_t)o * HW_TOT] = acc[o];
}

// ---------------- forward DFT over y as GEMM: T[row*32 + 2ky+c] = sum_y h[row,y]*W[y][2ky+c]
// W[y][2ky] = cos(2pi y ky/256), W[y][2ky+1] = -sin(...). Block: 128 rows x 32 j, 256 thr.
// Thread: jg = t&7 (j = 4jg..+3), rg = t>>3 (rows rg+32k, k<4). 16 acc.
// R8: twiddles rebuilt per 64-y chunk into Wc[64][32] (8KB) instead of a resident
// Ws[256][32] (32KB): LDS 45KB -> 3 blocks/CU (was 2).
__global__ void __launch_bounds__(256) dfty_kernel(
    const float* __restrict__ h, float* __restrict__ T)
{
    __shared__ float As[128][68];     // y-chunk of 64, padded (34.8 KB)
    __shared__ float Wc[64][32];      // per-chunk twiddles (8 KB)
    __shared__ float cs2[256], sn2[256];
    const int t = threadIdx.x;
    {
        float a = (float)t * PI2_256;
        cs2[t] = cosf(a); sn2[t] = sinf(a);
    }
    __syncthreads();

    const size_t rowbase = (size_t)blockIdx.x * 128;
    const int jg = t & 7, rg = t >> 3;
    float acc[4][4];
#pragma unroll
    for (int k = 0; k < 4; ++k)
#pragma unroll
        for (int q = 0; q < 4; ++q) acc[k][q] = 0.0f;

    for (int yc = 0; yc < 256; yc += 64) {
        if (yc) __syncthreads();   // protect As/Wc from previous iteration's readers
        // stage As[128][64]: 2048 float4; lane-consecutive = y-consecutive (coalesced)
#pragma unroll
        for (int it = 0; it < 8; ++it) {
            int idx = t + 256 * it;
            int rr = idx >> 4, c4 = idx & 15;
            float4 v = *(const float4*)(h + (rowbase + rr) * 256 + yc + c4 * 4);
            *(float4*)&As[rr][c4 * 4] = v;
        }
        // build Wc for this chunk: Wc[yl][2ky+c] for y = yc+yl
#pragma unroll
        for (int it = 0; it < 8; ++it) {
            int i = t + 256 * it;
            int yl = i >> 5, j = i & 31, ky = j >> 1;
            int m = ((yc + yl) * ky) & 255;
            Wc[yl][j] = (j & 1) ? -sn2[m] : cs2[m];
        }
        __syncthreads();
#pragma unroll 2
        for (int yy = 0; yy < 64; yy += 4) {
            float4 wv[4], av[4];
#pragma unroll
            for (int q = 0; q < 4; ++q) wv[q] = *(const float4*)&Wc[yy + q][jg * 4];
#pragma unroll
            for (int k = 0; k < 4; ++k) av[k] = *(const float4*)&As[rg + 32 * k][yy];
#pragma unroll
            for (int k = 0; k < 4; ++k)
#pragma unroll
                for (int q = 0; q < 4; ++q) {
                    float a = F4COMP(av[k], q);
                    acc[k][0] = fmaf(a, wv[q].x, acc[k][0]);
                    acc[k][1] = fmaf(a, wv[q].y, acc[k][1]);
                    acc[k][2] = fmaf(a, wv[q].z, acc[k][2]);
                    acc[k][3] = fmaf(a, wv[q].w, acc[k][3]);
                }
        }
    }
#pragma unroll
    for (int k = 0; k < 4; ++k) {
        float4 v = make_float4(acc[k][0], acc[k][1], acc[k][2], acc[k][3]);
        *(float4*)&T[(rowbase + rg + 32 * k) * 32 + jg * 4] = v;
    }
}

// ---------------- forward DFT over x: X[bc,kxi,ky] = sum_x T[bc,x,ky] * e^{-2pi i kx x/256}
__global__ void __launch_bounds__(512) dft2_kernel(
    const float2* __restrict__ T2, float2* __restrict__ X2)
{
    __shared__ float cs[256], sn[256];
    const int t = threadIdx.x;
    if (t < 256) {
        float a = (float)t * PI2_256;
        cs[t] = cosf(a); sn[t] = sinf(a);
    }
    __syncthreads();
    const int bc = blockIdx.x;
    const int ky = t & 15, kxi = t >> 4;
    const int kx = (kxi < 16) ? kxi : (224 + kxi);
    const float2* Tp = T2 + (size_t)bc * 4096 + ky;
    float xr = 0.0f, xi = 0.0f;
    int m = 0;
    for (int x = 0; x < 256; ++x) {
        float2 tv = Tp[(size_t)x * 16];
        float c = cs[m], s = sn[m];
        xr = fmaf(tv.x, c, fmaf(tv.y, s, xr));
        xi = fmaf(tv.y, c, fmaf(-tv.x, s, xi));
        m = (m + kx) & 255;
    }
    X2[(size_t)bc * 512 + t] = make_float2(xr, xi);
}

// ---------------- complex mode mixing
__global__ void __launch_bounds__(512) mix_kernel(
    const float2* __restrict__ X2, float2* __restrict__ Y2,
    const float* __restrict__ w1r, const float* __restrict__ w1i,
    const float* __restrict__ w2r, const float* __restrict__ w2i, int layer)
{
    const int bo = blockIdx.x;
    const int b = bo >> 6, o = bo & 63;
    const int t = threadIdx.x;
    const int ky = t & 15, kxi = t >> 4;
    const bool top = (kxi < 16);
    const int kxm = top ? kxi : (kxi - 16);
    const float* wr = top ? w1r : w2r;
    const float* wi = top ? w1i : w2i;
    float yr = 0.0f, yi = 0.0f;
    for (int i = 0; i < 64; ++i) {
        float2 xv = X2[((size_t)(b * 64 + i) * 32 + kxi) * 16 + ky];
        size_t widx = (((size_t)layer * 64 + i) * 64 + o) * 256 + (kxm * 16 + ky);
        float wrv = wr[widx], wiv = wi[widx];
        yr = fmaf(xv.x, wrv, fmaf(-xv.y, wiv, yr));
        yi = fmaf(xv.x, wiv, fmaf(xv.y, wrv, yi));
    }
    Y2[((size_t)(b * 64 + o) * 32 + kxi) * 16 + ky] = make_float2(yr, yi);
}

// ---------------- inverse DFT over x
__global__ void __launch_bounds__(256) idft1_kernel(
    const float2* __restrict__ Y2, float2* __restrict__ G2)
{
    __shared__ float cs[256], sn[256];
    const int t = threadIdx.x;
    {
        float a = (float)t * PI2_256;
        cs[t] = cosf(a); sn[t] = sinf(a);
    }
    __syncthreads();
    const int bo = blockIdx.x >> 4;
    const int xc = blockIdx.x & 15;
    const int ky = t & 15, xo = t >> 4;
    const int x = xc * 16 + xo;
    const float2* Yp = Y2 + (size_t)bo * 512 + ky;
    float gr = 0.0f, gi = 0.0f;
    for (int kxi = 0; kxi < 32; ++kxi) {
        float2 yv = Yp[(size_t)kxi * 16];
        int kx = (kxi < 16) ? kxi : (224 + kxi);
        int m = (kx * x) & 255;
        float c = cs[m], s = sn[m];
        gr = fmaf(yv.x, c, fmaf(-yv.y, s, gr));
        gi = fmaf(yv.x, s, fmaf(yv.y, c, gi));
    }
    G2[((size_t)bo * 256 + x) * 16 + ky] = make_float2(gr, gi);
}

// ---------------- fused pointwise conv + iDFT-y + add + GELU, in place on h.
__global__ void __launch_bounds__(1024) pwcomb_kernel(
    float* __restrict__ h, const float2* __restrict__ G2,
    const float* __restrict__ pw_w, const float* __restrict__ pw_b,
    int layer, int do_gelu)
{
    __shared__ float hs[64][256];     // [ci][y] 64 KB
    __shared__ float Wt[64][65];      // [ci][o] transposed, padded (16.6 KB)
    __shared__ float Gt[32][64];      // [j'][o] 8 KB
    __shared__ float Pt[32][256];     // [j'][y] 32 KB
    __shared__ float cs[256], sn[256];
    const int t = threadIdx.x;
    const int b = blockIdx.x >> 8;
    const int x = blockIdx.x & 255;
    if (t < 256) {
        float a = (float)t * PI2_256;
        cs[t] = cosf(a); sn[t] = sinf(a);
    }
    __syncthreads();

    // Wt[ci][o] from pw_w[layer][o][ci]
    const float* wl = pw_w + layer * 4096;
    for (int i = t; i < 4096; i += 1024) { int o = i >> 6, ci = i & 63; Wt[ci][o] = wl[i]; }
    // Gt from G2
    {
        int o = t >> 4, ky = t & 15;
        float2 g = G2[((size_t)(b * 64 + o) * 256 + x) * 16 + ky];
        Gt[2 * ky][o] = g.x;
        Gt[2 * ky + 1][o] = g.y;
    }
    // Pt[j'][y]: j'=2ky -> wk*cos(2pi ky y/256); j'=2ky+1 -> -wk*sin(...)
    const float inv = 1.0f / 65536.0f;
#pragma unroll
    for (int it = 0; it < 8; ++it) {
        int i = t + 1024 * it;
        int jp = i >> 8, y = i & 255, ky = jp >> 1;
        int m = (ky * y) & 255;
        float wk = (ky == 0) ? inv : 2.0f * inv;
        Pt[jp][y] = (jp & 1) ? -wk * sn[m] : wk * cs[m];
    }
    // stage hs (all reads of h precede the barrier; writes after -> in-place safe)
#pragma unroll
    for (int it = 0; it < 4; ++it) {
        int idx = t + 1024 * it;
        int ci = idx >> 6, c4 = idx & 63;
        float4 v = *(const float4*)(h + ((size_t)(b * 64 + ci) * 256 + x) * 256 + c4 * 4);
        *(float4*)&hs[ci][c4 * 4] = v;
    }
    __syncthreads();

    const int og = t & 15, yg = t >> 4;
    const float* bl = pw_b + layer * 64;
    float acc[4][4];   // [yj][oj]
#pragma unroll
    for (int oj = 0; oj < 4; ++oj) {
        float bv = bl[og * 4 + oj];
#pragma unroll
        for (int yj = 0; yj < 4; ++yj) acc[yj][oj] = bv;
    }
    // conv part: K = 64
    for (int ci = 0; ci < 64; ++ci) {
        float4 hv = *(const float4*)&hs[ci][yg * 4];
        float4 wv = *(const float4*)&Wt[ci][og * 4];
#pragma unroll
        for (int yj = 0; yj < 4; ++yj) {
            float a = F4COMP(hv, yj);
            acc[yj][0] = fmaf(a, wv.x, acc[yj][0]);
            acc[yj][1] = fmaf(a, wv.y, acc[yj][1]);
            acc[yj][2] = fmaf(a, wv.z, acc[yj][2]);
            acc[yj][3] = fmaf(a, wv.w, acc[yj][3]);
        }
    }
    // spectral part: K = 32
#pragma unroll 4
    for (int jp = 0; jp < 32; ++jp) {
        float4 pv = *(const float4*)&Pt[jp][yg * 4];
        float4 gv = *(const float4*)&Gt[jp][og * 4];
#pragma unroll
        for (int yj = 0; yj < 4; ++yj) {
            float a = F4COMP(pv, yj);
            acc[yj][0] = fmaf(a, gv.x, acc[yj][0]);
            acc[yj][1] = fmaf(a, gv.y, acc[yj][1]);
            acc[yj][2] = fmaf(a, gv.z, acc[yj][2]);
            acc[yj][3] = fmaf(a, gv.w, acc[yj][3]);
        }
    }
    // epilogue: gelu + store (float4 per o-row)
#pragma unroll
    for (int oj = 0; oj < 4; ++oj) {
        float4 v;
        v.x = acc[0][oj]; v.y = acc[1][oj]; v.z = acc[2][oj]; v.w = acc[3][oj];
        if (do_gelu) {
            v.x = gelu_fast(v.x); v.y = gelu_fast(v.y);
            v.z = gelu_fast(v.z); v.w = gelu_fast(v.w);
        }
        *(float4*)&h[((size_t)(b * 64 + og * 4 + oj) * 256 + x) * 256 + yg * 4] = v;
    }
}

// ---------------- tiny transpose: w1t[ci][hd] = fc1_w[hd][ci]  (64 x 128)
__global__ void __launch_bounds__(256) transpose_w1_kernel(
    const float* __restrict__ w1, float* __restrict__ w1t)
{
    int i = blockIdx.x * 256 + threadIdx.x;   // 8192 elements
    int ci = i >> 7, hd = i & 127;
    w1t[i] = w1[hd * 64 + ci];
}

// ---------------- fused projection: out = fc2(gelu(fc1(h))) per pixel.
// 512 thr, block = 128 px. Thread = 1 px x 32 hd (px = t&127, wave-pair wv = t>>7,
// hd = wv*32..+31 wave-uniform -> w1t/w2 rows via s_load). fc1: 1 ds_read_b32
// per ci + 32 reg FMA. gelu in regs. fc2: 20 partial dots in regs.
// R9 reduction (no atomics -- R8's ds_add_f32 added 170us of RMW stall):
// 2-stage tree via red[2][20][128] (20KB): wv2/3 ds_write partials; wv0/1 add
// in regs; wv1 writes combined; wv0 stores. LDS 52KB -> 3 blocks/CU, 24 waves.
__global__ void __launch_bounds__(512, 4) proj_kernel(
    const float* __restrict__ h,
    const float* __restrict__ w1t, const float* __restrict__ b1,
    const float* __restrict__ w2, const float* __restrict__ b2,
    float* __restrict__ out)
{
    __shared__ float hs[64][128];        // 32 KB
    __shared__ float red[2][20][128];    // 20 KB
    const int t = threadIdx.x;
    const int blk = blockIdx.x;
    const int b = blk >> 9;                 // 512 blocks per sample
    const int p0 = (blk & 511) << 7;        // pixel base

    // stage hs: 64 rows x 128 px = 2048 float4, coalesced
    {
        const float* hp = h + (size_t)b * 64 * HW_TOT + p0;
#pragma unroll
        for (int it = 0; it < 4; ++it) {
            int idx = t + 512 * it;
            int ci = idx >> 5, c4 = idx & 31;
            float4 v = *(const float4*)(hp + (size_t)ci * HW_TOT + c4 * 4);
            *(float4*)&hs[ci][c4 * 4] = v;
        }
    }
    __syncthreads();

    const int px = t & 127;
    const int wv = __builtin_amdgcn_readfirstlane(t >> 7);  // 0..3, wave-uniform
    const int hd0 = wv * 32;

    // fc1: acc[k] = b1[hd0+k] + sum_ci w1[hd0+k][ci] * h[ci][px]
    float acc[32];
#pragma unroll
    for (int k = 0; k < 32; ++k) acc[k] = b1[hd0 + k];
#pragma unroll 2
    for (int ci = 0; ci < 64; ++ci) {
        float a = hs[ci][px];
        const float* wr = w1t + ci * 128 + hd0;   // uniform -> s_load
#pragma unroll
        for (int k = 0; k < 32; ++k) acc[k] = fmaf(wr[k], a, acc[k]);
    }
    // gelu in registers
#pragma unroll
    for (int k = 0; k < 32; ++k) acc[k] = gelu_fast(acc[k]);

    // fc2 partials over this wave-pair's 32 hd
    float acc2[20];
#pragma unroll
    for (int o = 0; o < 20; ++o) {
        const float* w2r = w2 + o * 128 + hd0;    // uniform -> s_load
        float s0 = (wv == 0) ? b2[o] : 0.0f, s1 = 0.0f;
#pragma unroll
        for (int k = 0; k < 32; k += 2) {
            s0 = fmaf(w2r[k], acc[k], s0);
            s1 = fmaf(w2r[k + 1], acc[k + 1], s1);
        }
        acc2[o] = s0 + s1;
    }
    // 2-stage tree reduction, plain ds_writes (no atomics, no contention):
    // stage 1: wv2 -> red[0], wv3 -> red[1]
    if (wv >= 2) {
#pragma unroll
        for (int o = 0; o < 20; ++o) red[wv - 2][o][px] = acc2[o];
    }
    __syncthreads();
    if (wv < 2) {
#pragma unroll
        for (int o = 0; o < 20; ++o) acc2[o] += red[wv][o][px];
    }
    // stage 2: wv1 publishes its combined partial (same addresses it just read
    // -- own-thread RAW only, no cross-thread hazard before the barrier)
    if (wv == 1) {
#pragma unroll
        for (int o = 0; o < 20; ++o) red[1][o][px] = acc2[o];
    }
    __syncthreads();
    if (wv == 0) {
        float* op = out + (size_t)b * 20 * HW_TOT + p0 + px;
#pragma unroll
        for (int o = 0; o < 20; ++o)
            op[(size_t)o * HW_TOT] = acc2[o] + red[1][o][px];
    }
}

extern "C" void kernel_launch(void* const* d_in, const int* in_sizes, int n_in,
                              void* d_out, int out_size, void* d_ws, size_t ws_size,
                              hipStream_t stream)
{
    const float* x     = (const float*)d_in[0];
    const float* w1r   = (const float*)d_in[1];
    const float* w1i   = (const float*)d_in[2];
    const float* w2r   = (const float*)d_in[3];
    const float* w2i   = (const float*)d_in[4];
    const float* pw_w  = (const float*)d_in[5];
    const float* pw_b  = (const float*)d_in[6];
    const float* fc0_w = (const float*)d_in[7];
    const float* fc0_b = (const float*)d_in[8];
    const float* fc1_w = (const float*)d_in[9];
    const float* fc1_b = (const float*)d_in[10];
    const float* fc2_w = (const float*)d_in[11];
    const float* fc2_b = (const float*)d_in[12];
    float* out = (float*)d_out;
    float* ws  = (float*)d_ws;

    const size_t per_sample_floats = 4849664;
    int CB = 16;
    while (CB > 1 && (size_t)CB * per_sample_floats * 4 > ws_size) CB >>= 1;

    float*  h  = ws;
    float*  T  = ws + (size_t)CB * 4194304;
    float2* T2 = (float2*)T;
    float2* X2 = (float2*)(T + (size_t)CB * 524288);
    float2* Y2 = (float2*)(T + (size_t)CB * 524288 + (size_t)CB * 65536);
    float2* G2 = T2;   // reuse

    for (int c0 = 0; c0 < 16; c0 += CB) {
        const float* xc = x + (size_t)c0 * 20 * HW_TOT;
        float* oc = out + (size_t)c0 * 20 * HW_TOT;

        conv1x1_kernel<20, 64, 20>
            <<<dim3(256, CB), 256, 0, stream>>>(xc, fc0_w, fc0_b, h);

        for (int l = 0; l < 4; ++l) {
            dfty_kernel <<<CB * 128, 256, 0, stream>>>(h, T);
            dft2_kernel <<<CB * 64, 512, 0, stream>>>(T2, X2);
            mix_kernel  <<<CB * 64, 512, 0, stream>>>(X2, Y2, w1r, w1i, w2r, w2i, l);
            idft1_kernel<<<CB * 64 * 16, 256, 0, stream>>>(Y2, G2);
            pwcomb_kernel<<<CB * 256, 1024, 0, stream>>>(h, G2, pw_w, pw_b, l, (l < 3) ? 1 : 0);
        }

        // T/G2 region is dead after the last pwcomb: reuse for w1^T
        transpose_w1_kernel<<<32, 256, 0, stream>>>(fc1_w, T);
        proj_kernel<<<CB * 512, 512, 0, stream>>>(h, T, fc1_b, fc2_w, fc2_b, oc);
    }
}

// Round 7
// 2612.948 us; speedup vs baseline: 1.0394x; 1.0142x over previous
//
#include <hip/hip_runtime.h>
#include <hip/hip_bf16.h>

// FNO2d: B=16, CIN=20, H=W=256, WIDTH=64, M1=M2=16, NLAYERS=4, FC_HID=128, COUT=20
// Round 10:
// proj: RESTORED verbatim to R7's measured-best (361us; red[4][20][128], one
// barrier, all-thread epilogue). R8 (atomics) and R9 (tree) both regressed it;
// LDS granularity ~16KB means 52KB still = 2 blocks/CU, so the tree bought
// nothing and its extra barriers/divergence cost ~110us. Stop touching proj.
// pwcomb: phase-split LDS union. Conv phase needs {hs 64KB, Wt 16KB}; spectral
// phase needs {Gt 8KB, Pt 32KB}; acc carries in regs. Union = 80KB exactly ->
// 2 blocks/CU (32 waves, was 16). Wt unpadded (staging remapped o->lane so
// writes are row-contiguous); Pt built by direct cosf/sinf (no cs/sn tables);
// launch_bounds(1024,8) targets <=64 VGPR.
//
// Per-sample workspace (floats): h 4,194,304 | T/G 524,288 | X2 65,536 | Y2 65,536
// = 4,849,664 floats (19.4 MB); CB=16 -> 310 MB.

#define HW_TOT 65536
#define PI2_256 0.024543692606170259758f  // 2*pi/256

__device__ __forceinline__ float gelu_exact(float v) {
    return 0.5f * v * (1.0f + erff(v * 0.70710678118654752440f));
}
// Branch-free gelu: erf via Abramowitz-Stegun 7.1.26 (|abs err| <= 1.5e-7).
__device__ __forceinline__ float gelu_fast(float v) {
    float z  = v * 0.70710678118654752440f;
    float az = fabsf(z);
    float t  = __builtin_amdgcn_rcpf(fmaf(0.3275911f, az, 1.0f));
    float p  = t * (0.254829592f + t * (-0.284496736f + t * (1.421413741f +
               t * (-1.453152027f + t * 1.061405429f))));
    float e  = __expf(-az * az);
    float er = copysignf(1.0f - p * e, z);
    return 0.5f * v * (1.0f + er);
}
#define F4COMP(v, k) ((k)==0?(v).x:(k)==1?(v).y:(k)==2?(v).z:(v).w)

// ---------------- 1x1 conv (lift)
template<int CI, int CO, int WS>
__global__ void __launch_bounds__(256) conv1x1_kernel(
    const float* __restrict__ in, const float* __restrict__ w,
    const float* __restrict__ bias, float* __restrict__ out)
{
    const int b = blockIdx.y;
    const int p = blockIdx.x * 256 + threadIdx.x;
    const float* inp = in + (size_t)b * CI * HW_TOT + p;
    float acc[CO];
#pragma unroll
    for (int o = 0; o < CO; ++o) acc[o] = bias[o];
    for (int ci = 0; ci < CI; ++ci) {
        float hv = inp[(size_t)ci * HW_TOT];
#pragma unroll
        for (int o = 0; o < CO; ++o)
            acc[o] = fmaf(w[o * WS + ci], hv, acc[o]);
    }
    float* op = out + (size_t)b * CO * HW_TOT + p;
#pragma unroll
    for (int o = 0; o < CO; ++o) op[(size_t)o * HW_TOT] = acc[o];
}

// ---------------- forward DFT over y as GEMM: T[row*32 + 2ky+c] = sum_y h[row,y]*W[y][2ky+c]
// R8: twiddles rebuilt per 64-y chunk into Wc[64][32] (8KB); LDS 45KB.
__global__ void __launch_bounds__(256) dfty_kernel(
    const float* __restrict__ h, float* __restrict__ T)
{
    __shared__ float As[128][68];     // y-chunk of 64, padded (34.8 KB)
    __shared__ float Wc[64][32];      // per-chunk twiddles (8 KB)
    __shared__ float cs2[256], sn2[256];
    const int t = threadIdx.x;
    {
        float a = (float)t * PI2_256;
        cs2[t] = cosf(a); sn2[t] = sinf(a);
    }
    __syncthreads();

    const size_t rowbase = (size_t)blockIdx.x * 128;
    const int jg = t & 7, rg = t >> 3;
    float acc[4][4];
#pragma unroll
    for (int k = 0; k < 4; ++k)
#pragma unroll
        for (int q = 0; q < 4; ++q) acc[k][q] = 0.0f;

    for (int yc = 0; yc < 256; yc += 64) {
        if (yc) __syncthreads();   // protect As/Wc from previous iteration's readers
#pragma unroll
        for (int it = 0; it < 8; ++it) {
            int idx = t + 256 * it;
            int rr = idx >> 4, c4 = idx & 15;
            float4 v = *(const float4*)(h + (rowbase + rr) * 256 + yc + c4 * 4);
            *(float4*)&As[rr][c4 * 4] = v;
        }
        // build Wc for this chunk: Wc[yl][2ky+c] for y = yc+yl
#pragma unroll
        for (int it = 0; it < 8; ++it) {
            int i = t + 256 * it;
            int yl = i >> 5, j = i & 31, ky = j >> 1;
            int m = ((yc + yl) * ky) & 255;
            Wc[yl][j] = (j & 1) ? -sn2[m] : cs2[m];
        }
        __syncthreads();
#pragma unroll 2
        for (int yy = 0; yy < 64; yy += 4) {
            float4 wv[4], av[4];
#pragma unroll
            for (int q = 0; q < 4; ++q) wv[q] = *(const float4*)&Wc[yy + q][jg * 4];
#pragma unroll
            for (int k = 0; k < 4; ++k) av[k] = *(const float4*)&As[rg + 32 * k][yy];
#pragma unroll
            for (int k = 0; k < 4; ++k)
#pragma unroll
                for (int q = 0; q < 4; ++q) {
                    float a = F4COMP(av[k], q);
                    acc[k][0] = fmaf(a, wv[q].x, acc[k][0]);
                    acc[k][1] = fmaf(a, wv[q].y, acc[k][1]);
                    acc[k][2] = fmaf(a, wv[q].z, acc[k][2]);
                    acc[k][3] = fmaf(a, wv[q].w, acc[k][3]);
                }
        }
    }
#pragma unroll
    for (int k = 0; k < 4; ++k) {
        float4 v = make_float4(acc[k][0], acc[k][1], acc[k][2], acc[k][3]);
        *(float4*)&T[(rowbase + rg + 32 * k) * 32 + jg * 4] = v;
    }
}

// ---------------- forward DFT over x: X[bc,kxi,ky] = sum_x T[bc,x,ky] * e^{-2pi i kx x/256}
__global__ void __launch_bounds__(512) dft2_kernel(
    const float2* __restrict__ T2, float2* __restrict__ X2)
{
    __shared__ float cs[256], sn[256];
    const int t = threadIdx.x;
    if (t < 256) {
        float a = (float)t * PI2_256;
        cs[t] = cosf(a); sn[t] = sinf(a);
    }
    __syncthreads();
    const int bc = blockIdx.x;
    const int ky = t & 15, kxi = t >> 4;
    const int kx = (kxi < 16) ? kxi : (224 + kxi);
    const float2* Tp = T2 + (size_t)bc * 4096 + ky;
    float xr = 0.0f, xi = 0.0f;
    int m = 0;
    for (int x = 0; x < 256; ++x) {
        float2 tv = Tp[(size_t)x * 16];
        float c = cs[m], s = sn[m];
        xr = fmaf(tv.x, c, fmaf(tv.y, s, xr));
        xi = fmaf(tv.y, c, fmaf(-tv.x, s, xi));
        m = (m + kx) & 255;
    }
    X2[(size_t)bc * 512 + t] = make_float2(xr, xi);
}

// ---------------- complex mode mixing
__global__ void __launch_bounds__(512) mix_kernel(
    const float2* __restrict__ X2, float2* __restrict__ Y2,
    const float* __restrict__ w1r, const float* __restrict__ w1i,
    const float* __restrict__ w2r, const float* __restrict__ w2i, int layer)
{
    const int bo = blockIdx.x;
    const int b = bo >> 6, o = bo & 63;
    const int t = threadIdx.x;
    const int ky = t & 15, kxi = t >> 4;
    const bool top = (kxi < 16);
    const int kxm = top ? kxi : (kxi - 16);
    const float* wr = top ? w1r : w2r;
    const float* wi = top ? w1i : w2i;
    float yr = 0.0f, yi = 0.0f;
    for (int i = 0; i < 64; ++i) {
        float2 xv = X2[((size_t)(b * 64 + i) * 32 + kxi) * 16 + ky];
        size_t widx = (((size_t)layer * 64 + i) * 64 + o) * 256 + (kxm * 16 + ky);
        float wrv = wr[widx], wiv = wi[widx];
        yr = fmaf(xv.x, wrv, fmaf(-xv.y, wiv, yr));
        yi = fmaf(xv.x, wiv, fmaf(xv.y, wrv, yi));
    }
    Y2[((size_t)(b * 64 + o) * 32 + kxi) * 16 + ky] = make_float2(yr, yi);
}

// ---------------- inverse DFT over x
__global__ void __launch_bounds__(256) idft1_kernel(
    const float2* __restrict__ Y2, float2* __restrict__ G2)
{
    __shared__ float cs[256], sn[256];
    const int t = threadIdx.x;
    {
        float a = (float)t * PI2_256;
        cs[t] = cosf(a); sn[t] = sinf(a);
    }
    __syncthreads();
    const int bo = blockIdx.x >> 4;
    const int xc = blockIdx.x & 15;
    const int ky = t & 15, xo = t >> 4;
    const int x = xc * 16 + xo;
    const float2* Yp = Y2 + (size_t)bo * 512 + ky;
    float gr = 0.0f, gi = 0.0f;
    for (int kxi = 0; kxi < 32; ++kxi) {
        float2 yv = Yp[(size_t)kxi * 16];
        int kx = (kxi < 16) ? kxi : (224 + kxi);
        int m = (kx * x) & 255;
        float c = cs[m], s = sn[m];
        gr = fmaf(yv.x, c, fmaf(-yv.y, s, gr));
        gi = fmaf(yv.x, s, fmaf(yv.y, c, gi));
    }
    G2[((size_t)bo * 256 + x) * 16 + ky] = make_float2(gr, gi);
}

// ---------------- fused pointwise conv + iDFT-y + add + GELU, in place on h.
// R10: LDS phase-split union, 80KB exactly -> 2 blocks/CU (32 waves, was 16).
// Phase A: stage hs[64][256] (64KB) + Wt[64][64] (16KB, unpadded -- staging maps
// o->lane so ds writes are row-contiguous; reads at og*16 stride are 2-way=free),
// then conv K=64 loop. Barrier. Phase B: overlay Gt[32][64]+Pt[32][256] (40KB)
// on the same buffer (all hs/Wt reads completed); Pt via direct cosf/sinf
// (8 calls/thread one-time, no cs/sn tables). Then spectral K=32 loop + epilogue.
__global__ void __launch_bounds__(1024, 8) pwcomb_kernel(
    float* __restrict__ h, const float2* __restrict__ G2,
    const float* __restrict__ pw_w, const float* __restrict__ pw_b,
    int layer, int do_gelu)
{
    __shared__ float buf[20480];                       // 80 KB union
    float (*hs)[256] = (float (*)[256])buf;            // phase A: [64][256]
    float (*Wt)[64]  = (float (*)[64])(buf + 16384);   // phase A: [64][64]
    float (*Gt)[64]  = (float (*)[64])buf;             // phase B: [32][64]
    float (*Pt)[256] = (float (*)[256])(buf + 2048);   // phase B: [32][256]
    const int t = threadIdx.x;
    const int b = blockIdx.x >> 8;
    const int x = blockIdx.x & 255;

    // ---- phase A staging: Wt (o = lane -> row-contiguous LDS writes) + hs
    const float* wl = pw_w + layer * 4096;
#pragma unroll
    for (int it = 0; it < 4; ++it) {
        int i = t + 1024 * it;
        int o = i & 63, ci = i >> 6;
        Wt[ci][o] = wl[o * 64 + ci];   // global gather (L1-hot), LDS conflict-free
    }
#pragma unroll
    for (int it = 0; it < 4; ++it) {
        int idx = t + 1024 * it;
        int ci = idx >> 6, c4 = idx & 63;
        float4 v = *(const float4*)(h + ((size_t)(b * 64 + ci) * 256 + x) * 256 + c4 * 4);
        *(float4*)&hs[ci][c4 * 4] = v;
    }
    __syncthreads();

    const int og = t & 15, yg = t >> 4;
    const float* bl = pw_b + layer * 64;
    float acc[4][4];   // [yj][oj]
#pragma unroll
    for (int oj = 0; oj < 4; ++oj) {
        float bv = bl[og * 4 + oj];
#pragma unroll
        for (int yj = 0; yj < 4; ++yj) acc[yj][oj] = bv;
    }
    // conv part: K = 64 (reads hs, Wt)
    for (int ci = 0; ci < 64; ++ci) {
        float4 hv = *(const float4*)&hs[ci][yg * 4];
        float4 wv = *(const float4*)&Wt[ci][og * 4];
#pragma unroll
        for (int yj = 0; yj < 4; ++yj) {
            float a = F4COMP(hv, yj);
            acc[yj][0] = fmaf(a, wv.x, acc[yj][0]);
            acc[yj][1] = fmaf(a, wv.y, acc[yj][1]);
            acc[yj][2] = fmaf(a, wv.z, acc[yj][2]);
            acc[yj][3] = fmaf(a, wv.w, acc[yj][3]);
        }
    }
    __syncthreads();   // all hs/Wt reads done -> safe to overlay Gt/Pt

    // ---- phase B staging: Gt from G2; Pt by direct trig
    {
        int o = t >> 4, ky = t & 15;
        float2 g = G2[((size_t)(b * 64 + o) * 256 + x) * 16 + ky];
        Gt[2 * ky][o] = g.x;
        Gt[2 * ky + 1][o] = g.y;
    }
    const float inv = 1.0f / 65536.0f;
#pragma unroll
    for (int it = 0; it < 8; ++it) {
        int i = t + 1024 * it;
        int jp = i >> 8, y = i & 255, ky = jp >> 1;
        int m = (ky * y) & 255;
        float wk = (ky == 0) ? inv : 2.0f * inv;
        float ang = (float)m * PI2_256;
        Pt[jp][y] = (jp & 1) ? -wk * sinf(ang) : wk * cosf(ang);
    }
    __syncthreads();

    // spectral part: K = 32 (reads Pt, Gt)
#pragma unroll 4
    for (int jp = 0; jp < 32; ++jp) {
        float4 pv = *(const float4*)&Pt[jp][yg * 4];
        float4 gv = *(const float4*)&Gt[jp][og * 4];
#pragma unroll
        for (int yj = 0; yj < 4; ++yj) {
            float a = F4COMP(pv, yj);
            acc[yj][0] = fmaf(a, gv.x, acc[yj][0]);
            acc[yj][1] = fmaf(a, gv.y, acc[yj][1]);
            acc[yj][2] = fmaf(a, gv.z, acc[yj][2]);
            acc[yj][3] = fmaf(a, gv.w, acc[yj][3]);
        }
    }
    // epilogue: gelu + store (float4 per o-row)
#pragma unroll
    for (int oj = 0; oj < 4; ++oj) {
        float4 v;
        v.x = acc[0][oj]; v.y = acc[1][oj]; v.z = acc[2][oj]; v.w = acc[3][oj];
        if (do_gelu) {
            v.x = gelu_fast(v.x); v.y = gelu_fast(v.y);
            v.z = gelu_fast(v.z); v.w = gelu_fast(v.w);
        }
        *(float4*)&h[((size_t)(b * 64 + og * 4 + oj) * 256 + x) * 256 + yg * 4] = v;
    }
}

// ---------------- tiny transpose: w1t[ci][hd] = fc1_w[hd][ci]  (64 x 128)
__global__ void __launch_bounds__(256) transpose_w1_kernel(
    const float* __restrict__ w1, float* __restrict__ w1t)
{
    int i = blockIdx.x * 256 + threadIdx.x;   // 8192 elements
    int ci = i >> 7, hd = i & 127;
    w1t[i] = w1[hd * 64 + ci];
}

// ---------------- fused projection: out = fc2(gelu(fc1(h))) per pixel.
// VERBATIM R7 (measured 361us): 512 thr, block = 128 px. Thread = 1 px x 32 hd
// (px = t&127, wave-pair wv = t>>7, hd = wv*32..+31 wave-uniform -> w1t/w2 rows
// via s_load). fc1: 1 ds_read_b32 per ci + 32 reg FMA. gelu in regs. fc2: 20
// partial dots in regs; all 4 wave-pairs write red[wv], one barrier, all 512
// threads sum 4 partials for 5 outputs each. LDS 72KB -> 2 blocks/CU.
__global__ void __launch_bounds__(512, 4) proj_kernel(
    const float* __restrict__ h,
    const float* __restrict__ w1t, const float* __restrict__ b1,
    const float* __restrict__ w2, const float* __restrict__ b2,
    float* __restrict__ out)
{
    __shared__ float hs[64][128];        // 32 KB
    __shared__ float red[4][20][128];    // 40 KB
    const int t = threadIdx.x;
    const int blk = blockIdx.x;
    const int b = blk >> 9;                 // 512 blocks per sample
    const int p0 = (blk & 511) << 7;        // pixel base

    // stage hs: 64 rows x 128 px = 2048 float4, coalesced
    {
        const float* hp = h + (size_t)b * 64 * HW_TOT + p0;
#pragma unroll
        for (int it = 0; it < 4; ++it) {
            int idx = t + 512 * it;
            int ci = idx >> 5, c4 = idx & 31;
            float4 v = *(const float4*)(hp + (size_t)ci * HW_TOT + c4 * 4);
            *(float4*)&hs[ci][c4 * 4] = v;
        }
    }
    __syncthreads();

    const int px = t & 127;
    const int wv = __builtin_amdgcn_readfirstlane(t >> 7);  // 0..3, wave-uniform
    const int hd0 = wv * 32;

    // fc1: acc[k] = b1[hd0+k] + sum_ci w1[hd0+k][ci] * h[ci][px]
    float acc[32];
#pragma unroll
    for (int k = 0; k < 32; ++k) acc[k] = b1[hd0 + k];
#pragma unroll 2
    for (int ci = 0; ci < 64; ++ci) {
        float a = hs[ci][px];
        const float* wr = w1t + ci * 128 + hd0;   // uniform -> s_load
#pragma unroll
        for (int k = 0; k < 32; ++k) acc[k] = fmaf(wr[k], a, acc[k]);
    }
    // gelu in registers
#pragma unroll
    for (int k = 0; k < 32; ++k) acc[k] = gelu_fast(acc[k]);

    // fc2 partials over this wave-pair's 32 hd
    float acc2[20];
#pragma unroll
    for (int o = 0; o < 20; ++o) {
        const float* w2r = w2 + o * 128 + hd0;    // uniform -> s_load
        float s0 = (wv == 0) ? b2[o] : 0.0f, s1 = 0.0f;
#pragma unroll
        for (int k = 0; k < 32; k += 2) {
            s0 = fmaf(w2r[k], acc[k], s0);
            s1 = fmaf(w2r[k + 1], acc[k + 1], s1);
        }
        acc2[o] = s0 + s1;
    }
    // cross-wave reduction: plain writes, one barrier
#pragma unroll
    for (int o = 0; o < 20; ++o) red[wv][o][px] = acc2[o];
    __syncthreads();

    const int og = t >> 7;
    float* op = out + (size_t)b * 20 * HW_TOT + p0 + px;
#pragma unroll
    for (int j = 0; j < 5; ++j) {
        int o = og * 5 + j;
        float s = red[0][o][px] + red[1][o][px] + red[2][o][px] + red[3][o][px];
        op[(size_t)o * HW_TOT] = s;
    }
}

extern "C" void kernel_launch(void* const* d_in, const int* in_sizes, int n_in,
                              void* d_out, int out_size, void* d_ws, size_t ws_size,
                              hipStream_t stream)
{
    const float* x     = (const float*)d_in[0];
    const float* w1r   = (const float*)d_in[1];
    const float* w1i   = (const float*)d_in[2];
    const float* w2r   = (const float*)d_in[3];
    const float* w2i   = (const float*)d_in[4];
    const float* pw_w  = (const float*)d_in[5];
    const float* pw_b  = (const float*)d_in[6];
    const float* fc0_w = (const float*)d_in[7];
    const float* fc0_b = (const float*)d_in[8];
    const float* fc1_w = (const float*)d_in[9];
    const float* fc1_b = (const float*)d_in[10];
    const float* fc2_w = (const float*)d_in[11];
    const float* fc2_b = (const float*)d_in[12];
    float* out = (float*)d_out;
    float* ws  = (float*)d_ws;

    const size_t per_sample_floats = 4849664;
    int CB = 16;
    while (CB > 1 && (size_t)CB * per_sample_floats * 4 > ws_size) CB >>= 1;

    float*  h  = ws;
    float*  T  = ws + (size_t)CB * 4194304;
    float2* T2 = (float2*)T;
    float2* X2 = (float2*)(T + (size_t)CB * 524288);
    float2* Y2 = (float2*)(T + (size_t)CB * 524288 + (size_t)CB * 65536);
    float2* G2 = T2;   // reuse

    for (int c0 = 0; c0 < 16; c0 += CB) {
        const float* xc = x + (size_t)c0 * 20 * HW_TOT;
        float* oc = out + (size_t)c0 * 20 * HW_TOT;

        conv1x1_kernel<20, 64, 20>
            <<<dim3(256, CB), 256, 0, stream>>>(xc, fc0_w, fc0_b, h);

        for (int l = 0; l < 4; ++l) {
            dfty_kernel <<<CB * 128, 256, 0, stream>>>(h, T);
            dft2_kernel <<<CB * 64, 512, 0, stream>>>(T2, X2);
            mix_kernel  <<<CB * 64, 512, 0, stream>>>(X2, Y2, w1r, w1i, w2r, w2i, l);
            idft1_kernel<<<CB * 64 * 16, 256, 0, stream>>>(Y2, G2);
            pwcomb_kernel<<<CB * 256, 1024, 0, stream>>>(h, G2, pw_w, pw_b, l, (l < 3) ? 1 : 0);
        }

        // T/G2 region is dead after the last pwcomb: reuse for w1^T
        transpose_w1_kernel<<<32, 256, 0, stream>>>(fc1_w, T);
        proj_kernel<<<CB * 512, 512, 0, stream>>>(h, T, fc1_b, fc2_w, fc2_b, oc);
    }
}

// Round 8
// 2457.335 us; speedup vs baseline: 1.1052x; 1.0633x over previous
//
#include <hip/hip_runtime.h>
#include <hip/hip_bf16.h>

// FNO2d: B=16, CIN=20, H=W=256, WIDTH=64, M1=M2=16, NLAYERS=4, FC_HID=128, COUT=20
// Round 11: R10 postmortem -- proj's 361-vs-509us across rounds is pure clock scale
// (dur and hbm_gbps both ratio 1.41 with identical counters); proj is at its VALU
// instruction floor. Structural fix: FUSE proj into pwcomb l=3 (template<FUSE>).
// Phase C reuses the 80KB buf: h_final tile (padded [64][260]) overlaid on dead
// Gt/Pt, then proj's wave-uniform s_load GEMM (px=t&255, wf=t>>8, 2x16-hd passes,
// acc[16]+acc2[20] ~56 VGPR <= 64 so (1024,8) keeps 2 blocks/CU = 32 waves, 2x
// proj's occupancy), then the R7-proven one-barrier red[4][20][256] = exactly
// 20480 floats = whole buf (temporal overlay after last hnew read).
// Eliminates: proj dispatch + its h read (~130MB) + pwcomb l=3's h write (268MB)
// + proj staging/launch. l<3 instantiation is byte-identical to R10's pwcomb.
// w1^T goes into the dead Y2 region (after idft1 l=3; G2/T untouched).
//
// Per-sample workspace (floats): h 4,194,304 | T/G 524,288 | X2 65,536 | Y2 65,536
// = 4,849,664 floats (19.4 MB); CB=16 -> 310 MB.

#define HW_TOT 65536
#define PI2_256 0.024543692606170259758f  // 2*pi/256

__device__ __forceinline__ float gelu_exact(float v) {
    return 0.5f * v * (1.0f + erff(v * 0.70710678118654752440f));
}
// Branch-free gelu: erf via Abramowitz-Stegun 7.1.26 (|abs err| <= 1.5e-7).
__device__ __forceinline__ float gelu_fast(float v) {
    float z  = v * 0.70710678118654752440f;
    float az = fabsf(z);
    float t  = __builtin_amdgcn_rcpf(fmaf(0.3275911f, az, 1.0f));
    float p  = t * (0.254829592f + t * (-0.284496736f + t * (1.421413741f +
               t * (-1.453152027f + t * 1.061405429f))));
    float e  = __expf(-az * az);
    float er = copysignf(1.0f - p * e, z);
    return 0.5f * v * (1.0f + er);
}
#define F4COMP(v, k) ((k)==0?(v).x:(k)==1?(v).y:(k)==2?(v).z:(v).w)

// ---------------- 1x1 conv (lift)
template<int CI, int CO, int WS>
__global__ void __launch_bounds__(256) conv1x1_kernel(
    const float* __restrict__ in, const float* __restrict__ w,
    const float* __restrict__ bias, float* __restrict__ out)
{
    const int b = blockIdx.y;
    const int p = blockIdx.x * 256 + threadIdx.x;
    const float* inp = in + (size_t)b * CI * HW_TOT + p;
    float acc[CO];
#pragma unroll
    for (int o = 0; o < CO; ++o) acc[o] = bias[o];
    for (int ci = 0; ci < CI; ++ci) {
        float hv = inp[(size_t)ci * HW_TOT];
#pragma unroll
        for (int o = 0; o < CO; ++o)
            acc[o] = fmaf(w[o * WS + ci], hv, acc[o]);
    }
    float* op = out + (size_t)b * CO * HW_TOT + p;
#pragma unroll
    for (int o = 0; o < CO; ++o) op[(size_t)o * HW_TOT] = acc[o];
}

// ---------------- forward DFT over y as GEMM: T[row*32 + 2ky+c] = sum_y h[row,y]*W[y][2ky+c]
// R8: twiddles rebuilt per 64-y chunk into Wc[64][32] (8KB); LDS 45KB.
__global__ void __launch_bounds__(256) dfty_kernel(
    const float* __restrict__ h, float* __restrict__ T)
{
    __shared__ float As[128][68];     // y-chunk of 64, padded (34.8 KB)
    __shared__ float Wc[64][32];      // per-chunk twiddles (8 KB)
    __shared__ float cs2[256], sn2[256];
    const int t = threadIdx.x;
    {
        float a = (float)t * PI2_256;
        cs2[t] = cosf(a); sn2[t] = sinf(a);
    }
    __syncthreads();

    const size_t rowbase = (size_t)blockIdx.x * 128;
    const int jg = t & 7, rg = t >> 3;
    float acc[4][4];
#pragma unroll
    for (int k = 0; k < 4; ++k)
#pragma unroll
        for (int q = 0; q < 4; ++q) acc[k][q] = 0.0f;

    for (int yc = 0; yc < 256; yc += 64) {
        if (yc) __syncthreads();   // protect As/Wc from previous iteration's readers
#pragma unroll
        for (int it = 0; it < 8; ++it) {
            int idx = t + 256 * it;
            int rr = idx >> 4, c4 = idx & 15;
            float4 v = *(const float4*)(h + (rowbase + rr) * 256 + yc + c4 * 4);
            *(float4*)&As[rr][c4 * 4] = v;
        }
        // build Wc for this chunk: Wc[yl][2ky+c] for y = yc+yl
#pragma unroll
        for (int it = 0; it < 8; ++it) {
            int i = t + 256 * it;
            int yl = i >> 5, j = i & 31, ky = j >> 1;
            int m = ((yc + yl) * ky) & 255;
            Wc[yl][j] = (j & 1) ? -sn2[m] : cs2[m];
        }
        __syncthreads();
#pragma unroll 2
        for (int yy = 0; yy < 64; yy += 4) {
            float4 wv[4], av[4];
#pragma unroll
            for (int q = 0; q < 4; ++q) wv[q] = *(const float4*)&Wc[yy + q][jg * 4];
#pragma unroll
            for (int k = 0; k < 4; ++k) av[k] = *(const float4*)&As[rg + 32 * k][yy];
#pragma unroll
            for (int k = 0; k < 4; ++k)
#pragma unroll
                for (int q = 0; q < 4; ++q) {
                    float a = F4COMP(av[k], q);
                    acc[k][0] = fmaf(a, wv[q].x, acc[k][0]);
                    acc[k][1] = fmaf(a, wv[q].y, acc[k][1]);
                    acc[k][2] = fmaf(a, wv[q].z, acc[k][2]);
                    acc[k][3] = fmaf(a, wv[q].w, acc[k][3]);
                }
        }
    }
#pragma unroll
    for (int k = 0; k < 4; ++k) {
        float4 v = make_float4(acc[k][0], acc[k][1], acc[k][2], acc[k][3]);
        *(float4*)&T[(rowbase + rg + 32 * k) * 32 + jg * 4] = v;
    }
}

// ---------------- forward DFT over x: X[bc,kxi,ky] = sum_x T[bc,x,ky] * e^{-2pi i kx x/256}
__global__ void __launch_bounds__(512) dft2_kernel(
    const float2* __restrict__ T2, float2* __restrict__ X2)
{
    __shared__ float cs[256], sn[256];
    const int t = threadIdx.x;
    if (t < 256) {
        float a = (float)t * PI2_256;
        cs[t] = cosf(a); sn[t] = sinf(a);
    }
    __syncthreads();
    const int bc = blockIdx.x;
    const int ky = t & 15, kxi = t >> 4;
    const int kx = (kxi < 16) ? kxi : (224 + kxi);
    const float2* Tp = T2 + (size_t)bc * 4096 + ky;
    float xr = 0.0f, xi = 0.0f;
    int m = 0;
    for (int x = 0; x < 256; ++x) {
        float2 tv = Tp[(size_t)x * 16];
        float c = cs[m], s = sn[m];
        xr = fmaf(tv.x, c, fmaf(tv.y, s, xr));
        xi = fmaf(tv.y, c, fmaf(-tv.x, s, xi));
        m = (m + kx) & 255;
    }
    X2[(size_t)bc * 512 + t] = make_float2(xr, xi);
}

// ---------------- complex mode mixing
__global__ void __launch_bounds__(512) mix_kernel(
    const float2* __restrict__ X2, float2* __restrict__ Y2,
    const float* __restrict__ w1r, const float* __restrict__ w1i,
    const float* __restrict__ w2r, const float* __restrict__ w2i, int layer)
{
    const int bo = blockIdx.x;
    const int b = bo >> 6, o = bo & 63;
    const int t = threadIdx.x;
    const int ky = t & 15, kxi = t >> 4;
    const bool top = (kxi < 16);
    const int kxm = top ? kxi : (kxi - 16);
    const float* wr = top ? w1r : w2r;
    const float* wi = top ? w1i : w2i;
    float yr = 0.0f, yi = 0.0f;
    for (int i = 0; i < 64; ++i) {
        float2 xv = X2[((size_t)(b * 64 + i) * 32 + kxi) * 16 + ky];
        size_t widx = (((size_t)layer * 64 + i) * 64 + o) * 256 + (kxm * 16 + ky);
        float wrv = wr[widx], wiv = wi[widx];
        yr = fmaf(xv.x, wrv, fmaf(-xv.y, wiv, yr));
        yi = fmaf(xv.x, wiv, fmaf(xv.y, wrv, yi));
    }
    Y2[((size_t)(b * 64 + o) * 32 + kxi) * 16 + ky] = make_float2(yr, yi);
}

// ---------------- inverse DFT over x
__global__ void __launch_bounds__(256) idft1_kernel(
    const float2* __restrict__ Y2, float2* __restrict__ G2)
{
    __shared__ float cs[256], sn[256];
    const int t = threadIdx.x;
    {
        float a = (float)t * PI2_256;
        cs[t] = cosf(a); sn[t] = sinf(a);
    }
    __syncthreads();
    const int bo = blockIdx.x >> 4;
    const int xc = blockIdx.x & 15;
    const int ky = t & 15, xo = t >> 4;
    const int x = xc * 16 + xo;
    const float2* Yp = Y2 + (size_t)bo * 512 + ky;
    float gr = 0.0f, gi = 0.0f;
    for (int kxi = 0; kxi < 32; ++kxi) {
        float2 yv = Yp[(size_t)kxi * 16];
        int kx = (kxi < 16) ? kxi : (224 + kxi);
        int m = (kx * x) & 255;
        float c = cs[m], s = sn[m];
        gr = fmaf(yv.x, c, fmaf(-yv.y, s, gr));
        gi = fmaf(yv.x, s, fmaf(yv.y, c, gi));
    }
    G2[((size_t)bo * 256 + x) * 16 + ky] = make_float2(gr, gi);
}

// ---------------- fused pointwise conv + iDFT-y + add (+GELU | +projection).
// FUSE=0 (l<3): identical to R10's measured kernel: phase A (hs+Wt, conv K=64),
// phase B (Gt+Pt overlay, spectral K=32), gelu epilogue, h store. 80KB union,
// 2 blocks/CU.
// FUSE=1 (l=3): instead of storing h (dead), phase C runs the projection here:
// h_final tile -> buf as hn[64][260] (pad -> 2-way-free ds_write_b128); then
// px = t&255, wf = t>>8 (wave-uniform -> w1t/w2 rows via s_load), 2 passes x
// 16 hd: fc1 (64ci x 16 FMA per ds_read), gelu, fc2 partials into acc2[20];
// one-barrier reduction via red[4][20][256] = exactly 20480 floats = whole buf
// (temporal overlay, hn dead); all threads sum 4 partials, coalesced stores.
template<int FUSE>
__global__ void __launch_bounds__(1024, 8) pwcomb_kernel(
    float* __restrict__ h, const float2* __restrict__ G2,
    const float* __restrict__ pw_w, const float* __restrict__ pw_b,
    int layer, int do_gelu,
    const float* __restrict__ w1t, const float* __restrict__ fb1,
    const float* __restrict__ fw2, const float* __restrict__ fb2,
    float* __restrict__ out)
{
    __shared__ float buf[20480];                       // 80 KB union
    float (*hs)[256] = (float (*)[256])buf;            // phase A: [64][256]
    float (*Wt)[64]  = (float (*)[64])(buf + 16384);   // phase A: [64][64]
    float (*Gt)[64]  = (float (*)[64])buf;             // phase B: [32][64]
    float (*Pt)[256] = (float (*)[256])(buf + 2048);   // phase B: [32][256]
    const int t = threadIdx.x;
    const int b = blockIdx.x >> 8;
    const int x = blockIdx.x & 255;

    // ---- phase A staging: Wt (o = lane -> row-contiguous LDS writes) + hs
    const float* wl = pw_w + layer * 4096;
#pragma unroll
    for (int it = 0; it < 4; ++it) {
        int i = t + 1024 * it;
        int o = i & 63, ci = i >> 6;
        Wt[ci][o] = wl[o * 64 + ci];   // global gather (L1-hot), LDS conflict-free
    }
#pragma unroll
    for (int it = 0; it < 4; ++it) {
        int idx = t + 1024 * it;
        int ci = idx >> 6, c4 = idx & 63;
        float4 v = *(const float4*)(h + ((size_t)(b * 64 + ci) * 256 + x) * 256 + c4 * 4);
        *(float4*)&hs[ci][c4 * 4] = v;
    }
    __syncthreads();

    const int og = t & 15, yg = t >> 4;
    const float* bl = pw_b + layer * 64;
    float acc[4][4];   // [yj][oj]
#pragma unroll
    for (int oj = 0; oj < 4; ++oj) {
        float bv = bl[og * 4 + oj];
#pragma unroll
        for (int yj = 0; yj < 4; ++yj) acc[yj][oj] = bv;
    }
    // conv part: K = 64 (reads hs, Wt)
    for (int ci = 0; ci < 64; ++ci) {
        float4 hv = *(const float4*)&hs[ci][yg * 4];
        float4 wv = *(const float4*)&Wt[ci][og * 4];
#pragma unroll
        for (int yj = 0; yj < 4; ++yj) {
            float a = F4COMP(hv, yj);
            acc[yj][0] = fmaf(a, wv.x, acc[yj][0]);
            acc[yj][1] = fmaf(a, wv.y, acc[yj][1]);
            acc[yj][2] = fmaf(a, wv.z, acc[yj][2]);
            acc[yj][3] = fmaf(a, wv.w, acc[yj][3]);
        }
    }
    __syncthreads();   // all hs/Wt reads done -> safe to overlay Gt/Pt

    // ---- phase B staging: Gt from G2; Pt by direct trig
    {
        int o = t >> 4, ky = t & 15;
        float2 g = G2[((size_t)(b * 64 + o) * 256 + x) * 16 + ky];
        Gt[2 * ky][o] = g.x;
        Gt[2 * ky + 1][o] = g.y;
    }
    const float inv = 1.0f / 65536.0f;
#pragma unroll
    for (int it = 0; it < 8; ++it) {
        int i = t + 1024 * it;
        int jp = i >> 8, y = i & 255, ky = jp >> 1;
        int m = (ky * y) & 255;
        float wk = (ky == 0) ? inv : 2.0f * inv;
        float ang = (float)m * PI2_256;
        Pt[jp][y] = (jp & 1) ? -wk * sinf(ang) : wk * cosf(ang);
    }
    __syncthreads();

    // spectral part: K = 32 (reads Pt, Gt)
#pragma unroll 4
    for (int jp = 0; jp < 32; ++jp) {
        float4 pv = *(const float4*)&Pt[jp][yg * 4];
        float4 gv = *(const float4*)&Gt[jp][og * 4];
#pragma unroll
        for (int yj = 0; yj < 4; ++yj) {
            float a = F4COMP(pv, yj);
            acc[yj][0] = fmaf(a, gv.x, acc[yj][0]);
            acc[yj][1] = fmaf(a, gv.y, acc[yj][1]);
            acc[yj][2] = fmaf(a, gv.z, acc[yj][2]);
            acc[yj][3] = fmaf(a, gv.w, acc[yj][3]);
        }
    }

    if (!FUSE) {
        // epilogue: gelu + store (float4 per o-row)
#pragma unroll
        for (int oj = 0; oj < 4; ++oj) {
            float4 v;
            v.x = acc[0][oj]; v.y = acc[1][oj]; v.z = acc[2][oj]; v.w = acc[3][oj];
            if (do_gelu) {
                v.x = gelu_fast(v.x); v.y = gelu_fast(v.y);
                v.z = gelu_fast(v.z); v.w = gelu_fast(v.w);
            }
            *(float4*)&h[((size_t)(b * 64 + og * 4 + oj) * 256 + x) * 256 + yg * 4] = v;
        }
        return;
    }

    // ---- phase C (l=3): projection. h_final tile -> buf as hn[64][260] (padded).
    __syncthreads();   // Pt/Gt reads done -> safe to overlay hn
#pragma unroll
    for (int oj = 0; oj < 4; ++oj) {
        float4 v = make_float4(acc[0][oj], acc[1][oj], acc[2][oj], acc[3][oj]);
        *(float4*)&buf[(og * 4 + oj) * 260 + yg * 4] = v;   // hn[o][y], pad 260
    }
    __syncthreads();

    const int px = t & 255;
    const int wf = __builtin_amdgcn_readfirstlane(t >> 8);  // 0..3, wave-uniform
    float acc2[20];
#pragma unroll
    for (int o = 0; o < 20; ++o) acc2[o] = (wf == 0) ? fb2[o] : 0.0f;

#pragma unroll
    for (int pass = 0; pass < 2; ++pass) {
        const int hd0 = wf * 32 + pass * 16;
        float fa[16];
#pragma unroll
        for (int k = 0; k < 16; ++k) fa[k] = fb1[hd0 + k];
#pragma unroll 2
        for (int ci = 0; ci < 64; ++ci) {
            float a = buf[ci * 260 + px];             // lanes px-consecutive: conflict-free
            const float* wr = w1t + ci * 128 + hd0;   // wave-uniform -> s_load
#pragma unroll
            for (int k = 0; k < 16; ++k) fa[k] = fmaf(wr[k], a, fa[k]);
        }
#pragma unroll
        for (int k = 0; k < 16; ++k) fa[k] = gelu_fast(fa[k]);
#pragma unroll
        for (int o = 0; o < 20; ++o) {
            const float* w2r = fw2 + o * 128 + hd0;   // wave-uniform -> s_load
            float s0 = 0.0f, s1 = 0.0f;
#pragma unroll
            for (int k = 0; k < 16; k += 2) {
                s0 = fmaf(w2r[k], fa[k], s0);
                s1 = fmaf(w2r[k + 1], fa[k + 1], s1);
            }
            acc2[o] += s0 + s1;
        }
    }
    __syncthreads();   // all hn reads done -> safe to overlay red[4][20][256]
#pragma unroll
    for (int o = 0; o < 20; ++o) buf[(wf * 20 + o) * 256 + px] = acc2[o];
    __syncthreads();

    float* op = out + (size_t)b * 20 * HW_TOT + x * 256 + px;
#pragma unroll
    for (int j = 0; j < 5; ++j) {
        int o = wf * 5 + j;
        float s = buf[o * 256 + px] + buf[(20 + o) * 256 + px]
                + buf[(40 + o) * 256 + px] + buf[(60 + o) * 256 + px];
        op[(size_t)o * HW_TOT] = s;   // lanes px-consecutive: coalesced
    }
}

// ---------------- tiny transpose: w1t[ci][hd] = fc1_w[hd][ci]  (64 x 128)
__global__ void __launch_bounds__(256) transpose_w1_kernel(
    const float* __restrict__ w1, float* __restrict__ w1t)
{
    int i = blockIdx.x * 256 + threadIdx.x;   // 8192 elements
    int ci = i >> 7, hd = i & 127;
    w1t[i] = w1[hd * 64 + ci];
}

extern "C" void kernel_launch(void* const* d_in, const int* in_sizes, int n_in,
                              void* d_out, int out_size, void* d_ws, size_t ws_size,
                              hipStream_t stream)
{
    const float* x     = (const float*)d_in[0];
    const float* w1r   = (const float*)d_in[1];
    const float* w1i   = (const float*)d_in[2];
    const float* w2r   = (const float*)d_in[3];
    const float* w2i   = (const float*)d_in[4];
    const float* pw_w  = (const float*)d_in[5];
    const float* pw_b  = (const float*)d_in[6];
    const float* fc0_w = (const float*)d_in[7];
    const float* fc0_b = (const float*)d_in[8];
    const float* fc1_w = (const float*)d_in[9];
    const float* fc1_b = (const float*)d_in[10];
    const float* fc2_w = (const float*)d_in[11];
    const float* fc2_b = (const float*)d_in[12];
    float* out = (float*)d_out;
    float* ws  = (float*)d_ws;

    const size_t per_sample_floats = 4849664;
    int CB = 16;
    while (CB > 1 && (size_t)CB * per_sample_floats * 4 > ws_size) CB >>= 1;

    float*  h  = ws;
    float*  T  = ws + (size_t)CB * 4194304;
    float2* T2 = (float2*)T;
    float2* X2 = (float2*)(T + (size_t)CB * 524288);
    float2* Y2 = (float2*)(T + (size_t)CB * 524288 + (size_t)CB * 65536);
    float2* G2 = T2;   // reuse

    for (int c0 = 0; c0 < 16; c0 += CB) {
        const float* xc = x + (size_t)c0 * 20 * HW_TOT;
        float* oc = out + (size_t)c0 * 20 * HW_TOT;

        conv1x1_kernel<20, 64, 20>
            <<<dim3(256, CB), 256, 0, stream>>>(xc, fc0_w, fc0_b, h);

        for (int l = 0; l < 3; ++l) {
            dfty_kernel <<<CB * 128, 256, 0, stream>>>(h, T);
            dft2_kernel <<<CB * 64, 512, 0, stream>>>(T2, X2);
            mix_kernel  <<<CB * 64, 512, 0, stream>>>(X2, Y2, w1r, w1i, w2r, w2i, l);
            idft1_kernel<<<CB * 64 * 16, 256, 0, stream>>>(Y2, G2);
            pwcomb_kernel<0><<<CB * 256, 1024, 0, stream>>>(
                h, G2, pw_w, pw_b, l, 1,
                nullptr, nullptr, nullptr, nullptr, nullptr);
        }

        // layer 3: spectral pipeline, then fused pwcomb+projection
        dfty_kernel <<<CB * 128, 256, 0, stream>>>(h, T);
        dft2_kernel <<<CB * 64, 512, 0, stream>>>(T2, X2);
        mix_kernel  <<<CB * 64, 512, 0, stream>>>(X2, Y2, w1r, w1i, w2r, w2i, 3);
        idft1_kernel<<<CB * 64 * 16, 256, 0, stream>>>(Y2, G2);
        // Y2 region is dead after idft1 l=3: reuse for w1^T (G2/T untouched)
        float* w1t_buf = (float*)Y2;
        transpose_w1_kernel<<<32, 256, 0, stream>>>(fc1_w, w1t_buf);
        pwcomb_kernel<1><<<CB * 256, 1024, 0, stream>>>(
            h, G2, pw_w, pw_b, 3, 0,
            w1t_buf, fc1_b, fc2_w, fc2_b, oc);
    }
}

// Round 10
// 2128.367 us; speedup vs baseline: 1.2760x; 1.1546x over previous
//
#include <hip/hip_runtime.h>
#include <hip/hip_bf16.h>

// FNO2d: B=16, CIN=20, H=W=256, WIDTH=64, M1=M2=16, NLAYERS=4, FC_HID=128, COUT=20
// Round 13 = Round 12 resubmitted verbatim (R12 bench was an infra failure:
// "MI355X container failed twice" -- no pytest/rocprof stage ran, so no verdict
// on the kernel; barrier-uniformity and LDS-overlay audit re-passed).
// R12 theory: pwcomb profiled at 610us/dispatch x4 = ~75% of runtime, VGPR=32
// (squeezed), 1e7 bank conflicts; static audit (130us VALU / 205us LDS) far
// below measured -> R10 structure wastes the LDS port (2 b128 per 16 FMA,
// 4-of-16-lane broadcasts, uncoalesced Wt gather, 16-way Gt staging).
// Port proj's wave-uniform-weights pattern (R7, +45%): wave owns o-quad
// (uniform -> conv weights via s_load_dwordx4 straight from pw_w, Wt buffer
// deleted); lane owns y-quad -> 4 contiguous b128 + 4 s_loads per 64 FMA.
// Spectral: Gt broadcast b128 (uniform addr), Gt padded [32][68] (4-way
// staging), Pt from cs/sn tables (R9-proven) parked in buf spare space.
// LDS exactly 80KB -> 2 blocks/CU. Coalesced 1KB/wave h stores.
//
// Per-sample workspace (floats): h 4,194,304 | T/G 524,288 | X2 65,536 | Y2 65,536
// = 4,849,664 floats (19.4 MB); CB=16 -> 310 MB.

#define HW_TOT 65536
#define PI2_256 0.024543692606170259758f  // 2*pi/256

__device__ __forceinline__ float gelu_exact(float v) {
    return 0.5f * v * (1.0f + erff(v * 0.70710678118654752440f));
}
// Branch-free gelu: erf via Abramowitz-Stegun 7.1.26 (|abs err| <= 1.5e-7).
__device__ __forceinline__ float gelu_fast(float v) {
    float z  = v * 0.70710678118654752440f;
    float az = fabsf(z);
    float t  = __builtin_amdgcn_rcpf(fmaf(0.3275911f, az, 1.0f));
    float p  = t * (0.254829592f + t * (-0.284496736f + t * (1.421413741f +
               t * (-1.453152027f + t * 1.061405429f))));
    float e  = __expf(-az * az);
    float er = copysignf(1.0f - p * e, z);
    return 0.5f * v * (1.0f + er);
}
#define F4COMP(v, k) ((k)==0?(v).x:(k)==1?(v).y:(k)==2?(v).z:(v).w)

// ---------------- 1x1 conv (lift)
template<int CI, int CO, int WS>
__global__ void __launch_bounds__(256) conv1x1_kernel(
    const float* __restrict__ in, const float* __restrict__ w,
    const float* __restrict__ bias, float* __restrict__ out)
{
    const int b = blockIdx.y;
    const int p = blockIdx.x * 256 + threadIdx.x;
    const float* inp = in + (size_t)b * CI * HW_TOT + p;
    float acc[CO];
#pragma unroll
    for (int o = 0; o < CO; ++o) acc[o] = bias[o];
    for (int ci = 0; ci < CI; ++ci) {
        float hv = inp[(size_t)ci * HW_TOT];
#pragma unroll
        for (int o = 0; o < CO; ++o)
            acc[o] = fmaf(w[o * WS + ci], hv, acc[o]);
    }
    float* op = out + (size_t)b * CO * HW_TOT + p;
#pragma unroll
    for (int o = 0; o < CO; ++o) op[(size_t)o * HW_TOT] = acc[o];
}

// ---------------- forward DFT over y as GEMM: T[row*32 + 2ky+c] = sum_y h[row,y]*W[y][2ky+c]
// R8: twiddles rebuilt per 64-y chunk into Wc[64][32] (8KB); LDS 45KB.
__global__ void __launch_bounds__(256) dfty_kernel(
    const float* __restrict__ h, float* __restrict__ T)
{
    __shared__ float As[128][68];     // y-chunk of 64, padded (34.8 KB)
    __shared__ float Wc[64][32];      // per-chunk twiddles (8 KB)
    __shared__ float cs2[256], sn2[256];
    const int t = threadIdx.x;
    {
        float a = (float)t * PI2_256;
        cs2[t] = cosf(a); sn2[t] = sinf(a);
    }
    __syncthreads();

    const size_t rowbase = (size_t)blockIdx.x * 128;
    const int jg = t & 7, rg = t >> 3;
    float acc[4][4];
#pragma unroll
    for (int k = 0; k < 4; ++k)
#pragma unroll
        for (int q = 0; q < 4; ++q) acc[k][q] = 0.0f;

    for (int yc = 0; yc < 256; yc += 64) {
        if (yc) __syncthreads();   // protect As/Wc from previous iteration's readers
#pragma unroll
        for (int it = 0; it < 8; ++it) {
            int idx = t + 256 * it;
            int rr = idx >> 4, c4 = idx & 15;
            float4 v = *(const float4*)(h + (rowbase + rr) * 256 + yc + c4 * 4);
            *(float4*)&As[rr][c4 * 4] = v;
        }
        // build Wc for this chunk: Wc[yl][2ky+c] for y = yc+yl
#pragma unroll
        for (int it = 0; it < 8; ++it) {
            int i = t + 256 * it;
            int yl = i >> 5, j = i & 31, ky = j >> 1;
            int m = ((yc + yl) * ky) & 255;
            Wc[yl][j] = (j & 1) ? -sn2[m] : cs2[m];
        }
        __syncthreads();
#pragma unroll 2
        for (int yy = 0; yy < 64; yy += 4) {
            float4 wv[4], av[4];
#pragma unroll
            for (int q = 0; q < 4; ++q) wv[q] = *(const float4*)&Wc[yy + q][jg * 4];
#pragma unroll
            for (int k = 0; k < 4; ++k) av[k] = *(const float4*)&As[rg + 32 * k][yy];
#pragma unroll
            for (int k = 0; k < 4; ++k)
#pragma unroll
                for (int q = 0; q < 4; ++q) {
                    float a = F4COMP(av[k], q);
                    acc[k][0] = fmaf(a, wv[q].x, acc[k][0]);
                    acc[k][1] = fmaf(a, wv[q].y, acc[k][1]);
                    acc[k][2] = fmaf(a, wv[q].z, acc[k][2]);
                    acc[k][3] = fmaf(a, wv[q].w, acc[k][3]);
                }
        }
    }
#pragma unroll
    for (int k = 0; k < 4; ++k) {
        float4 v = make_float4(acc[k][0], acc[k][1], acc[k][2], acc[k][3]);
        *(float4*)&T[(rowbase + rg + 32 * k) * 32 + jg * 4] = v;
    }
}

// ---------------- forward DFT over x: X[bc,kxi,ky] = sum_x T[bc,x,ky] * e^{-2pi i kx x/256}
__global__ void __launch_bounds__(512) dft2_kernel(
    const float2* __restrict__ T2, float2* __restrict__ X2)
{
    __shared__ float cs[256], sn[256];
    const int t = threadIdx.x;
    if (t < 256) {
        float a = (float)t * PI2_256;
        cs[t] = cosf(a); sn[t] = sinf(a);
    }
    __syncthreads();
    const int bc = blockIdx.x;
    const int ky = t & 15, kxi = t >> 4;
    const int kx = (kxi < 16) ? kxi : (224 + kxi);
    const float2* Tp = T2 + (size_t)bc * 4096 + ky;
    float xr = 0.0f, xi = 0.0f;
    int m = 0;
    for (int x = 0; x < 256; ++x) {
        float2 tv = Tp[(size_t)x * 16];
        float c = cs[m], s = sn[m];
        xr = fmaf(tv.x, c, fmaf(tv.y, s, xr));
        xi = fmaf(tv.y, c, fmaf(-tv.x, s, xi));
        m = (m + kx) & 255;
    }
    X2[(size_t)bc * 512 + t] = make_float2(xr, xi);
}

// ---------------- complex mode mixing
__global__ void __launch_bounds__(512) mix_kernel(
    const float2* __restrict__ X2, float2* __restrict__ Y2,
    const float* __restrict__ w1r, const float* __restrict__ w1i,
    const float* __restrict__ w2r, const float* __restrict__ w2i, int layer)
{
    const int bo = blockIdx.x;
    const int b = bo >> 6, o = bo & 63;
    const int t = threadIdx.x;
    const int ky = t & 15, kxi = t >> 4;
    const bool top = (kxi < 16);
    const int kxm = top ? kxi : (kxi - 16);
    const float* wr = top ? w1r : w2r;
    const float* wi = top ? w1i : w2i;
    float yr = 0.0f, yi = 0.0f;
    for (int i = 0; i < 64; ++i) {
        float2 xv = X2[((size_t)(b * 64 + i) * 32 + kxi) * 16 + ky];
        size_t widx = (((size_t)layer * 64 + i) * 64 + o) * 256 + (kxm * 16 + ky);
        float wrv = wr[widx], wiv = wi[widx];
        yr = fmaf(xv.x, wrv, fmaf(-xv.y, wiv, yr));
        yi = fmaf(xv.x, wiv, fmaf(xv.y, wrv, yi));
    }
    Y2[((size_t)(b * 64 + o) * 32 + kxi) * 16 + ky] = make_float2(yr, yi);
}

// ---------------- inverse DFT over x
__global__ void __launch_bounds__(256) idft1_kernel(
    const float2* __restrict__ Y2, float2* __restrict__ G2)
{
    __shared__ float cs[256], sn[256];
    const int t = threadIdx.x;
    {
        float a = (float)t * PI2_256;
        cs[t] = cosf(a); sn[t] = sinf(a);
    }
    __syncthreads();
    const int bo = blockIdx.x >> 4;
    const int xc = blockIdx.x & 15;
    const int ky = t & 15, xo = t >> 4;
    const int x = xc * 16 + xo;
    const float2* Yp = Y2 + (size_t)bo * 512 + ky;
    float gr = 0.0f, gi = 0.0f;
    for (int kxi = 0; kxi < 32; ++kxi) {
        float2 yv = Yp[(size_t)kxi * 16];
        int kx = (kxi < 16) ? kxi : (224 + kxi);
        int m = (kx * x) & 255;
        float c = cs[m], s = sn[m];
        gr = fmaf(yv.x, c, fmaf(-yv.y, s, gr));
        gi = fmaf(yv.x, s, fmaf(yv.y, c, gi));
    }
    G2[((size_t)bo * 256 + x) * 16 + ky] = make_float2(gr, gi);
}

// ---------------- fused pointwise conv + iDFT-y + add (+GELU | +projection).
// R12 structure: 1024 thr = 16 waves. Wave w owns o-quad ow = 4w (wave-uniform);
// lane owns y-quad yq = 4*lane. Conv K=64: per 4-ci: 4 contiguous ds_read_b128
// (1KB/wave, conflict-free) + 4 s_load_dwordx4 from pw_w (uniform, SGPR operands)
// -> 64 FMA. Spectral K=32: per jp: pv b128 (contiguous) + Gt broadcast b128
// (uniform addr). Gt[32][68] pad -> 4-way staging. Pt from cs/sn tables in buf
// spare [16384,16896). LDS exactly 80KB (buf[20480]) -> 2 blocks/CU.
// FUSE=1 (l=3): phase C projection as R11: hn[64][260] overlay, wave-uniform
// fc1/fc2 s_load GEMM, red[4][20][256] one-barrier reduction, coalesced out.
template<int FUSE>
__global__ void __launch_bounds__(1024, 8) pwcomb_kernel(
    float* __restrict__ h, const float2* __restrict__ G2,
    const float* __restrict__ pw_w, const float* __restrict__ pw_b,
    int layer, int do_gelu,
    const float* __restrict__ w1t, const float* __restrict__ fb1,
    const float* __restrict__ fw2, const float* __restrict__ fb2,
    float* __restrict__ out)
{
    __shared__ float buf[20480];                       // 80 KB union
    float (*hs)[256] = (float (*)[256])buf;            // phase A: [64][256] = 16384
    float (*Gt)[68]  = (float (*)[68])buf;             // phase B: [32][68]  = 2176
    float (*Pt)[256] = (float (*)[256])(buf + 2176);   // phase B: [32][256] = 8192
    float* cs2 = buf + 16384;                          // [256] spare region
    float* sn2 = buf + 16640;                          // [256]
    const int t = threadIdx.x;
    const int b = blockIdx.x >> 8;
    const int x = blockIdx.x & 255;

    // tables (dead after phase-B staging; overlaid by phase C)
    if (t < 256) {
        float a = (float)t * PI2_256;
        cs2[t] = cosf(a); sn2[t] = sinf(a);
    }
    // ---- phase A staging: hs only (weights come via scalar path)
#pragma unroll
    for (int it = 0; it < 4; ++it) {
        int idx = t + 1024 * it;
        int ci = idx >> 6, c4 = idx & 63;
        float4 v = *(const float4*)(h + ((size_t)(b * 64 + ci) * 256 + x) * 256 + c4 * 4);
        *(float4*)&hs[ci][c4 * 4] = v;
    }
    __syncthreads();

    const int lane = t & 63;
    const int ow = __builtin_amdgcn_readfirstlane(t >> 6) * 4;  // wave-uniform o-quad
    const int yq = lane * 4;

    const float* bl = pw_b + layer * 64;
    float acc[4][4];   // [yj][oj]: output (ch = ow+oj, y = yq+yj)
#pragma unroll
    for (int oj = 0; oj < 4; ++oj) {
        float bv = bl[ow + oj];
#pragma unroll
        for (int yj = 0; yj < 4; ++yj) acc[yj][oj] = bv;
    }
    // conv part: K = 64 (hs b128 + s_load weights)
    const float* wbase = pw_w + layer * 4096;   // [o][ci]
#pragma unroll 2
    for (int cc = 0; cc < 64; cc += 4) {
        float4 wva[4];
#pragma unroll
        for (int oj = 0; oj < 4; ++oj)
            wva[oj] = *(const float4*)(wbase + (ow + oj) * 64 + cc);  // uniform -> s_load
#pragma unroll
        for (int k = 0; k < 4; ++k) {
            float4 hv = *(const float4*)&hs[cc + k][yq];
#pragma unroll
            for (int oj = 0; oj < 4; ++oj) {
                float w = F4COMP(wva[oj], k);
                acc[0][oj] = fmaf(hv.x, w, acc[0][oj]);
                acc[1][oj] = fmaf(hv.y, w, acc[1][oj]);
                acc[2][oj] = fmaf(hv.z, w, acc[2][oj]);
                acc[3][oj] = fmaf(hv.w, w, acc[3][oj]);
            }
        }
    }
    __syncthreads();   // all hs reads done -> safe to overlay Gt/Pt

    // ---- phase B staging: Gt from G2 (padded rows, 4-way); Pt from tables
    {
        int o = t >> 4, ky = t & 15;
        float2 g = G2[((size_t)(b * 64 + o) * 256 + x) * 16 + ky];
        Gt[2 * ky][o] = g.x;
        Gt[2 * ky + 1][o] = g.y;
    }
    const float inv = 1.0f / 65536.0f;
#pragma unroll
    for (int it = 0; it < 8; ++it) {
        int i = t + 1024 * it;
        int jp = i >> 8, y = i & 255, ky = jp >> 1;
        int m = (ky * y) & 255;
        float wk = (ky == 0) ? inv : 2.0f * inv;
        Pt[jp][y] = (jp & 1) ? -wk * sn2[m] : wk * cs2[m];
    }
    __syncthreads();

    // spectral part: K = 32 (Pt contiguous b128 + Gt broadcast b128)
#pragma unroll 4
    for (int jp = 0; jp < 32; ++jp) {
        float4 pv = *(const float4*)&Pt[jp][yq];
        float4 gv = *(const float4*)&Gt[jp][ow];   // uniform addr -> broadcast
#pragma unroll
        for (int yj = 0; yj < 4; ++yj) {
            float a = F4COMP(pv, yj);
            acc[yj][0] = fmaf(a, gv.x, acc[yj][0]);
            acc[yj][1] = fmaf(a, gv.y, acc[yj][1]);
            acc[yj][2] = fmaf(a, gv.z, acc[yj][2]);
            acc[yj][3] = fmaf(a, gv.w, acc[yj][3]);
        }
    }

    if (!FUSE) {
        // epilogue: gelu + store; lane-consecutive y -> 1KB/wave coalesced
#pragma unroll
        for (int oj = 0; oj < 4; ++oj) {
            float4 v = make_float4(acc[0][oj], acc[1][oj], acc[2][oj], acc[3][oj]);
            if (do_gelu) {
                v.x = gelu_fast(v.x); v.y = gelu_fast(v.y);
                v.z = gelu_fast(v.z); v.w = gelu_fast(v.w);
            }
            *(float4*)&h[((size_t)(b * 64 + ow + oj) * 256 + x) * 256 + yq] = v;
        }
        return;
    }

    // ---- phase C (l=3): projection. h_final tile -> buf as hn[64][260] (padded).
    __syncthreads();   // Pt/Gt reads done -> safe to overlay hn (tables dead too)
#pragma unroll
    for (int oj = 0; oj < 4; ++oj) {
        float4 v = make_float4(acc[0][oj], acc[1][oj], acc[2][oj], acc[3][oj]);
        *(float4*)&buf[(ow + oj) * 260 + yq] = v;   // hn[ch][y], pad 260
    }
    __syncthreads();

    const int px = t & 255;
    const int wf = __builtin_amdgcn_readfirstlane(t >> 8);  // 0..3, wave-uniform
    float acc2[20];
#pragma unroll
    for (int o = 0; o < 20; ++o) acc2[o] = (wf == 0) ? fb2[o] : 0.0f;

#pragma unroll
    for (int pass = 0; pass < 2; ++pass) {
        const int hd0 = wf * 32 + pass * 16;
        float fa[16];
#pragma unroll
        for (int k = 0; k < 16; ++k) fa[k] = fb1[hd0 + k];
#pragma unroll 2
        for (int ci = 0; ci < 64; ++ci) {
            float a = buf[ci * 260 + px];             // lanes px-consecutive: conflict-free
            const float* wr = w1t + ci * 128 + hd0;   // wave-uniform -> s_load
#pragma unroll
            for (int k = 0; k < 16; ++k) fa[k] = fmaf(wr[k], a, fa[k]);
        }
#pragma unroll
        for (int k = 0; k < 16; ++k) fa[k] = gelu_fast(fa[k]);
#pragma unroll
        for (int o = 0; o < 20; ++o) {
            const float* w2r = fw2 + o * 128 + hd0;   // wave-uniform -> s_load
            float s0 = 0.0f, s1 = 0.0f;
#pragma unroll
            for (int k = 0; k < 16; k += 2) {
                s0 = fmaf(w2r[k], fa[k], s0);
                s1 = fmaf(w2r[k + 1], fa[k + 1], s1);
            }
            acc2[o] += s0 + s1;
        }
    }
    __syncthreads();   // all hn reads done -> safe to overlay red[4][20][256]
#pragma unroll
    for (int o = 0; o < 20; ++o) buf[(wf * 20 + o) * 256 + px] = acc2[o];
    __syncthreads();

    float* op = out + (size_t)b * 20 * HW_TOT + x * 256 + px;
#pragma unroll
    for (int j = 0; j < 5; ++j) {
        int o = wf * 5 + j;
        float s = buf[o * 256 + px] + buf[(20 + o) * 256 + px]
                + buf[(40 + o) * 256 + px] + buf[(60 + o) * 256 + px];
        op[(size_t)o * HW_TOT] = s;   // lanes px-consecutive: coalesced
    }
}

// ---------------- tiny transpose: w1t[ci][hd] = fc1_w[hd][ci]  (64 x 128)
__global__ void __launch_bounds__(256) transpose_w1_kernel(
    const float* __restrict__ w1, float* __restrict__ w1t)
{
    int i = blockIdx.x * 256 + threadIdx.x;   // 8192 elements
    int ci = i >> 7, hd = i & 127;
    w1t[i] = w1[hd * 64 + ci];
}

extern "C" void kernel_launch(void* const* d_in, const int* in_sizes, int n_in,
                              void* d_out, int out_size, void* d_ws, size_t ws_size,
                              hipStream_t stream)
{
    const float* x     = (const float*)d_in[0];
    const float* w1r   = (const float*)d_in[1];
    const float* w1i   = (const float*)d_in[2];
    const float* w2r   = (const float*)d_in[3];
    const float* w2i   = (const float*)d_in[4];
    const float* pw_w  = (const float*)d_in[5];
    const float* pw_b  = (const float*)d_in[6];
    const float* fc0_w = (const float*)d_in[7];
    const float* fc0_b = (const float*)d_in[8];
    const float* fc1_w = (const float*)d_in[9];
    const float* fc1_b = (const float*)d_in[10];
    const float* fc2_w = (const float*)d_in[11];
    const float* fc2_b = (const float*)d_in[12];
    float* out = (float*)d_out;
    float* ws  = (float*)d_ws;

    const size_t per_sample_floats = 4849664;
    int CB = 16;
    while (CB > 1 && (size_t)CB * per_sample_floats * 4 > ws_size) CB >>= 1;

    float*  h  = ws;
    float*  T  = ws + (size_t)CB * 4194304;
    float2* T2 = (float2*)T;
    float2* X2 = (float2*)(T + (size_t)CB * 524288);
    float2* Y2 = (float2*)(T + (size_t)CB * 524288 + (size_t)CB * 65536);
    float2* G2 = T2;   // reuse

    for (int c0 = 0; c0 < 16; c0 += CB) {
        const float* xc = x + (size_t)c0 * 20 * HW_TOT;
        float* oc = out + (size_t)c0 * 20 * HW_TOT;

        conv1x1_kernel<20, 64, 20>
            <<<dim3(256, CB), 256, 0, stream>>>(xc, fc0_w, fc0_b, h);

        for (int l = 0; l < 3; ++l) {
            dfty_kernel <<<CB * 128, 256, 0, stream>>>(h, T);
            dft2_kernel <<<CB * 64, 512, 0, stream>>>(T2, X2);
            mix_kernel  <<<CB * 64, 512, 0, stream>>>(X2, Y2, w1r, w1i, w2r, w2i, l);
            idft1_kernel<<<CB * 64 * 16, 256, 0, stream>>>(Y2, G2);
            pwcomb_kernel<0><<<CB * 256, 1024, 0, stream>>>(
                h, G2, pw_w, pw_b, l, 1,
                nullptr, nullptr, nullptr, nullptr, nullptr);
        }

        // layer 3: spectral pipeline, then fused pwcomb+projection
        dfty_kernel <<<CB * 128, 256, 0, stream>>>(h, T);
        dft2_kernel <<<CB * 64, 512, 0, stream>>>(T2, X2);
        mix_kernel  <<<CB * 64, 512, 0, stream>>>(X2, Y2, w1r, w1i, w2r, w2i, 3);
        idft1_kernel<<<CB * 64 * 16, 256, 0, stream>>>(Y2, G2);
        // Y2 region is dead after idft1 l=3: reuse for w1^T (G2/T untouched)
        float* w1t_buf = (float*)Y2;
        transpose_w1_kernel<<<32, 256, 0, stream>>>(fc1_w, w1t_buf);
        pwcomb_kernel<1><<<CB * 256, 1024, 0, stream>>>(
            h, G2, pw_w, pw_b, 3, 0,
            w1t_buf, fc1_b, fc2_w, fc2_b, oc);
    }
}